// Round 1
// baseline (662.541 us; speedup 1.0000x reference)
//
#include <hip/hip_runtime.h>

#define NL 32768L

typedef __bf16 bf16x8 __attribute__((ext_vector_type(8)));
typedef float f32x4 __attribute__((ext_vector_type(4)));

__device__ __forceinline__ unsigned short f2bf(float f) {
  unsigned int u = __float_as_uint(f);
  u += 0x7FFFu + ((u >> 16) & 1u);   // round-to-nearest-even
  return (unsigned short)(u >> 16);
}

__device__ __forceinline__ void gload16(const void* g, void* l) {
  __builtin_amdgcn_global_load_lds((const __attribute__((address_space(1))) void*)g,
                                   (__attribute__((address_space(3))) void*)l, 16, 0, 0);
}

// ---- prep: x f32 interleaved (mul,d) -> bf16 d-major planes --------------
// Xp layout (elems): l0 [N][512] @0 ; l1 k planes [N][256] @ N*512 + k*N*256 ;
//                    l2 k planes [N][128] @ N*1280 + k*N*128
__global__ void prep_x_kernel(const float* __restrict__ x, unsigned short* __restrict__ Xp) {
  long i = (long)blockIdx.x * blockDim.x + threadIdx.x;
  if (i < NL * 512) {
    long n = i >> 9, u = i & 511;
    Xp[i] = f2bf(x[n * 1920 + u]);
  } else if (i < NL * 768) {
    long j = i - NL * 512;
    long n = j >> 8, u = j & 255;
    const float* s = x + n * 1920 + 512 + u * 3;
    unsigned short* d = Xp + NL * 512 + n * 256 + u;
    d[0]        = f2bf(s[0]);
    d[NL * 256] = f2bf(s[1]);
    d[NL * 512] = f2bf(s[2]);
  } else if (i < NL * 896) {
    long j = i - NL * 768;
    long n = j >> 7, u = j & 127;
    const float* s = x + n * 1920 + 1280 + u * 5;
    unsigned short* d = Xp + NL * 1280 + n * 128 + u;
#pragma unroll
    for (int k = 0; k < 5; ++k) d[k * NL * 128] = f2bf(s[k]);
  }
}

// ---- prep: W [R=K][C=NN] f32 -> Wt [NN][K] bf16 (transposed) -------------
__global__ void prep_wt_kernel(const float* __restrict__ w, unsigned short* __restrict__ wt,
                               int R, int C) {
  int i = blockIdx.x * blockDim.x + threadIdx.x;
  if (i >= R * C) return;
  int c = i / R, r = i - c * R;
  wt[i] = f2bf(w[(long)r * C + c]);   // wt[c][r] = w[r][c]
}

// ---- plane-batched GEMM ---------------------------------------------------
// Y_p[n,v] = sum_u A_p[n,u] * W[u,v], A_p bf16 planes [M][K], Wt bf16 [NN][K].
// MODE 0: K1 -> normact across planes -> bf16 planes out (planeOut stride)
// MODE 1: K2, P==1 -> f32 direct write to out[row*1920 + outOff + col]
// MODE 2: K2, P>1  -> LDS re-interleave -> coalesced f32 writes
template <int P, int BN, int K, int NN, int MODE>
__global__ __launch_bounds__(256) void gemm_k(
    const unsigned short* __restrict__ Ap, long planeA,
    const unsigned short* __restrict__ Wt,
    void* __restrict__ outp, long planeOut, int outOff, float sc) {
  constexpr int BM = 128, BK = 32;
  constexpr int FN = BN / 16;
  extern __shared__ char smem[];
  unsigned short* sA = (unsigned short*)smem;   // P * BM * BK
  unsigned short* sB = sA + P * BM * BK;        // BN * BK

  const int tid = threadIdx.x;
  const int lane = tid & 63, wv = tid >> 6;
  const int fr = lane & 15, fq = lane >> 4;     // frag col / k-group
  const int m0 = blockIdx.x * BM;
  const int n0 = blockIdx.y * BN;

  f32x4 acc[P][2][FN];
#pragma unroll
  for (int p = 0; p < P; ++p)
#pragma unroll
    for (int a = 0; a < 2; ++a)
#pragma unroll
      for (int b = 0; b < FN; ++b) acc[p][a][b] = (f32x4){0.f, 0.f, 0.f, 0.f};

  for (int k0 = 0; k0 < K; k0 += BK) {
    // stage A planes: each plane 128x32 bf16 = 512 16B-chunks, 2 per thread
#pragma unroll
    for (int p = 0; p < P; ++p) {
#pragma unroll
      for (int it = 0; it < 2; ++it) {
        int c = it * 256 + tid;
        int row = c >> 2, kk = (c & 3) * 8;
        gload16(Ap + p * planeA + (long)(m0 + row) * K + k0 + kk,
                sA + p * BM * BK + c * 8);
      }
    }
    // stage B (Wt rows are contiguous in K): BN*4 chunks
    if constexpr (BN == 64) {
      int c = tid, row = c >> 2, kk = (c & 3) * 8;
      gload16(Wt + (long)(n0 + row) * K + k0 + kk, sB + c * 8);
    } else {
      if (tid < BN * 4) {
        int c = tid, row = c >> 2, kk = (c & 3) * 8;
        gload16(Wt + (long)(n0 + row) * K + k0 + kk, sB + c * 8);
      }
    }
    asm volatile("s_waitcnt vmcnt(0)" ::: "memory");
    __syncthreads();

    bf16x8 bvv[FN];
#pragma unroll
    for (int fn = 0; fn < FN; ++fn)
      bvv[fn] = *(const bf16x8*)(sB + (fn * 16 + fr) * BK + fq * 8);
#pragma unroll
    for (int p = 0; p < P; ++p) {
#pragma unroll
      for (int fm = 0; fm < 2; ++fm) {
        bf16x8 av = *(const bf16x8*)(sA + p * BM * BK + (wv * 32 + fm * 16 + fr) * BK + fq * 8);
#pragma unroll
        for (int fn = 0; fn < FN; ++fn)
          acc[p][fm][fn] =
              __builtin_amdgcn_mfma_f32_16x16x32_bf16(av, bvv[fn], acc[p][fm][fn], 0, 0, 0);
      }
    }
    __syncthreads();
  }

  if constexpr (MODE == 0) {
    unsigned short* H = (unsigned short*)outp;
#pragma unroll
    for (int fm = 0; fm < 2; ++fm)
#pragma unroll
      for (int fn = 0; fn < FN; ++fn)
#pragma unroll
        for (int r = 0; r < 4; ++r) {
          float vs[P];
          float n2 = 0.f;
#pragma unroll
          for (int p = 0; p < P; ++p) {
            float v = acc[p][fm][fn][r] * sc;
            vs[p] = v;
            n2 += v * v;
          }
          float nm = sqrtf(n2);
          float sg = 1.f / (1.f + __expf(-nm));   // silu(n)/n == sigmoid(n)
          long row = m0 + wv * 32 + fm * 16 + fq * 4 + r;
          int col = n0 + fn * 16 + fr;
#pragma unroll
          for (int p = 0; p < P; ++p)
            H[p * planeOut + row * NN + col] = f2bf(vs[p] * sg);
        }
  } else if constexpr (MODE == 1) {
    float* O = (float*)outp;
#pragma unroll
    for (int fm = 0; fm < 2; ++fm)
#pragma unroll
      for (int fn = 0; fn < FN; ++fn)
#pragma unroll
        for (int r = 0; r < 4; ++r) {
          long row = m0 + wv * 32 + fm * 16 + fq * 4 + r;
          int col = n0 + fn * 16 + fr;
          O[row * 1920 + outOff + col] = acc[0][fm][fn][r] * sc;
        }
  } else {
    // re-interleave: per wave stage 16 rows x (BN*P) f32, then coalesced write
    float* st = (float*)smem + wv * (16 * BN * P);
    float* O = (float*)outp;
#pragma unroll
    for (int fm = 0; fm < 2; ++fm) {
#pragma unroll
      for (int fn = 0; fn < FN; ++fn)
#pragma unroll
        for (int r = 0; r < 4; ++r)
#pragma unroll
          for (int p = 0; p < P; ++p)
            st[(fq * 4 + r) * BN * P + (fn * 16 + fr) * P + p] = acc[p][fm][fn][r] * sc;
      __syncthreads();
      for (int e = lane; e < 16 * BN * P; e += 64) {
        int rl = e / (BN * P), cc = e - rl * (BN * P);
        long row = m0 + wv * 32 + fm * 16 + rl;
        O[row * 1920 + outOff + n0 * P + cc] = st[e];
      }
      __syncthreads();
    }
  }
}

extern "C" void kernel_launch(void* const* d_in, const int* in_sizes, int n_in,
                              void* d_out, int out_size, void* d_ws, size_t ws_size,
                              hipStream_t stream) {
  const float* x = (const float*)d_in[0];
  const float* w1_0 = (const float*)d_in[1];
  const float* w1_1 = (const float*)d_in[2];
  const float* w1_2 = (const float*)d_in[3];
  const float* w2_0 = (const float*)d_in[4];
  const float* w2_1 = (const float*)d_in[5];
  const float* w2_2 = (const float*)d_in[6];
  float* out = (float*)d_out;

  unsigned short* Xp = (unsigned short*)d_ws;      // N*1920 bf16
  unsigned short* Hp = Xp + NL * 1920;             // N*3840 bf16
  unsigned short* Wt1_0 = Hp + NL * 3840;          // [1024][512]
  unsigned short* Wt1_1 = Wt1_0 + 524288;          // [512][256]
  unsigned short* Wt1_2 = Wt1_1 + 131072;          // [256][128]
  unsigned short* Wt2_0 = Wt1_2 + 32768;           // [512][1024]
  unsigned short* Wt2_1 = Wt2_0 + 524288;          // [256][512]
  unsigned short* Wt2_2 = Wt2_1 + 131072;          // [128][256]

  {
    long total = NL * 896;
    prep_x_kernel<<<dim3((unsigned)((total + 255) / 256)), dim3(256), 0, stream>>>(x, Xp);
  }
  prep_wt_kernel<<<(512 * 1024 + 255) / 256, 256, 0, stream>>>(w1_0, Wt1_0, 512, 1024);
  prep_wt_kernel<<<(256 * 512 + 255) / 256, 256, 0, stream>>>(w1_1, Wt1_1, 256, 512);
  prep_wt_kernel<<<(128 * 256 + 255) / 256, 256, 0, stream>>>(w1_2, Wt1_2, 128, 256);
  prep_wt_kernel<<<(1024 * 512 + 255) / 256, 256, 0, stream>>>(w2_0, Wt2_0, 1024, 512);
  prep_wt_kernel<<<(512 * 256 + 255) / 256, 256, 0, stream>>>(w2_1, Wt2_1, 512, 256);
  prep_wt_kernel<<<(256 * 128 + 255) / 256, 256, 0, stream>>>(w2_2, Wt2_2, 256, 128);

  const float s512 = 0.04419417382f;  // 1/sqrt(512)
  const float s256 = 0.0625f;         // 1/sqrt(256)
  const float s128 = 0.08838834765f;  // 1/sqrt(128)
  const float s1024 = 0.03125f;       // 1/sqrt(1024)

  // Linear1 + NormAct -> Hp planes (bf16)
  gemm_k<1, 64, 512, 1024, 0><<<dim3(256, 16), 256, 12288, stream>>>(
      Xp, 0, Wt1_0, Hp, 0, 0, s512);
  gemm_k<3, 64, 256, 512, 0><<<dim3(256, 8), 256, 28672, stream>>>(
      Xp + NL * 512, NL * 256, Wt1_1, Hp + NL * 1024, NL * 512, 0, s256);
  gemm_k<5, 32, 128, 256, 0><<<dim3(256, 8), 256, 43008, stream>>>(
      Xp + NL * 1280, NL * 128, Wt1_2, Hp + NL * 2560, NL * 256, 0, s128);

  // Linear2 -> out (f32, interleaved layout)
  gemm_k<1, 64, 1024, 512, 1><<<dim3(256, 8), 256, 12288, stream>>>(
      Hp, 0, Wt2_0, out, 0, 0, s1024);
  gemm_k<3, 64, 512, 256, 2><<<dim3(256, 4), 256, 49152, stream>>>(
      Hp + NL * 1024, NL * 512, Wt2_1, out, 0, 512, s512);
  gemm_k<5, 32, 256, 128, 2><<<dim3(256, 4), 256, 43008, stream>>>(
      Hp + NL * 2560, NL * 256, Wt2_2, out, 0, 1280, s256);
}

// Round 2
// 504.138 us; speedup vs baseline: 1.3142x; 1.3142x over previous
//
#include <hip/hip_runtime.h>

#define NL 32768L

typedef __bf16 bf16x8 __attribute__((ext_vector_type(8)));
typedef float f32x4 __attribute__((ext_vector_type(4)));

__device__ __forceinline__ unsigned short f2bf(float f) {
  unsigned int u = __float_as_uint(f);
  u += 0x7FFFu + ((u >> 16) & 1u);   // round-to-nearest-even
  return (unsigned short)(u >> 16);
}

__device__ __forceinline__ void gload16(const void* g, void* l) {
  __builtin_amdgcn_global_load_lds((const __attribute__((address_space(1))) void*)g,
                                   (__attribute__((address_space(3))) void*)l, 16, 0, 0);
}

// ---- combined prep: x -> bf16 d-major planes, weights -> transposed bf16 ----
// Xp: l0 [N][512] @0 ; l1 planes [N][256] @ N*512 + p*N*256 ; l2 planes [N][128] @ N*1280 + p*N*128
// W (bf16, [NN][K] each): Wt1_0@0  Wt1_1@524288  Wt1_2@655360  Wt2_0@688128  Wt2_1@1212416  Wt2_2@1343488
__global__ void prep_kernel(const float* __restrict__ x,
                            const float* __restrict__ w1_0, const float* __restrict__ w1_1,
                            const float* __restrict__ w1_2, const float* __restrict__ w2_0,
                            const float* __restrict__ w2_1, const float* __restrict__ w2_2,
                            unsigned short* __restrict__ Xp, unsigned short* __restrict__ W) {
  long i = (long)blockIdx.x * blockDim.x + threadIdx.x;
  if (i < NL * 512) {
    long n = i >> 9, u = i & 511;
    Xp[i] = f2bf(x[n * 1920 + u]);
  } else if (i < NL * 768) {
    long j = i - NL * 512;
    long n = j >> 8, u = j & 255;
    const float* s = x + n * 1920 + 512 + u * 3;
    unsigned short* d = Xp + NL * 512 + n * 256 + u;
    d[0]        = f2bf(s[0]);
    d[NL * 256] = f2bf(s[1]);
    d[NL * 512] = f2bf(s[2]);
  } else if (i < NL * 896) {
    long j = i - NL * 768;
    long n = j >> 7, u = j & 127;
    const float* s = x + n * 1920 + 1280 + u * 5;
    unsigned short* d = Xp + NL * 1280 + n * 128 + u;
#pragma unroll
    for (int k = 0; k < 5; ++k) d[k * NL * 128] = f2bf(s[k]);
  } else {
    long j = i - NL * 896;
    if (j < 524288) {            // w1_0: K=512, C=1024
      int c = (int)(j >> 9), r = (int)(j & 511);
      W[j] = f2bf(w1_0[(long)r * 1024 + c]);
    } else if (j < 655360) {     // w1_1: K=256, C=512
      long t = j - 524288; int c = (int)(t >> 8), r = (int)(t & 255);
      W[j] = f2bf(w1_1[(long)r * 512 + c]);
    } else if (j < 688128) {     // w1_2: K=128, C=256
      long t = j - 655360; int c = (int)(t >> 7), r = (int)(t & 127);
      W[j] = f2bf(w1_2[(long)r * 256 + c]);
    } else if (j < 1212416) {    // w2_0: K=1024, C=512
      long t = j - 688128; int c = (int)(t >> 10), r = (int)(t & 1023);
      W[j] = f2bf(w2_0[(long)r * 512 + c]);
    } else if (j < 1343488) {    // w2_1: K=512, C=256
      long t = j - 1212416; int c = (int)(t >> 9), r = (int)(t & 511);
      W[j] = f2bf(w2_1[(long)r * 256 + c]);
    } else if (j < 1376256) {    // w2_2: K=256, C=128
      long t = j - 1343488; int c = (int)(t >> 8), r = (int)(t & 255);
      W[j] = f2bf(w2_2[(long)r * 128 + c]);
    }
  }
}

// ---- plane-batched GEMM v2 -------------------------------------------------
// 1D grid, XCD-swizzled, n-tile fastest. DBUF=1: 2-phase double-buffered staging.
// MODE 0: normact across planes -> bf16 planes. MODE 1: f32 direct (P==1).
// MODE 2: LDS re-interleave -> coalesced f32.
template <int P, int BN, int K, int NN, int MODE, int DBUF>
__global__ __launch_bounds__(256) void gemm_k(
    const unsigned short* __restrict__ Ap, long planeA,
    const unsigned short* __restrict__ Wt,
    void* __restrict__ outp, long planeOut, int outOff, float sc, int nx) {
  constexpr int BM = 128, BK = 32;
  constexpr int FN = BN / 16;
  constexpr int ABUF = P * BM * BK;       // elems
  constexpr int BUFE = ABUF + BN * BK;    // elems per stage buffer
  extern __shared__ char smem[];
  unsigned short* s0 = (unsigned short*)smem;

  const int tid = threadIdx.x;
  const int lane = tid & 63, wv = tid >> 6;
  const int fr = lane & 15, fq = lane >> 4;

  const int nwg = gridDim.x;
  const int bid = blockIdx.x;
  const int wg = (bid & 7) * (nwg >> 3) + (bid >> 3);   // bijective: nwg % 8 == 0
  const long m0 = (long)(wg / nx) * BM;
  const int n0 = (wg % nx) * BN;

  f32x4 acc[P][2][FN];
#pragma unroll
  for (int p = 0; p < P; ++p)
#pragma unroll
    for (int a = 0; a < 2; ++a)
#pragma unroll
      for (int b = 0; b < FN; ++b) acc[p][a][b] = (f32x4){0.f, 0.f, 0.f, 0.f};

  auto stage = [&](unsigned short* buf, int k0) {
#pragma unroll
    for (int p = 0; p < P; ++p)
#pragma unroll
      for (int it = 0; it < 2; ++it) {
        int c = it * 256 + tid;
        int row = c >> 2, kk = (c & 3) * 8;
        gload16(Ap + p * planeA + (m0 + row) * K + k0 + kk, buf + p * BM * BK + c * 8);
      }
    if constexpr (BN >= 64) {
#pragma unroll
      for (int it = 0; it < BN / 64; ++it) {
        int c = it * 256 + tid;
        int row = c >> 2, kk = (c & 3) * 8;
        gload16(Wt + (long)(n0 + row) * K + k0 + kk, buf + ABUF + c * 8);
      }
    } else {
      if (tid < BN * 4) {
        int c = tid, row = c >> 2, kk = (c & 3) * 8;
        gload16(Wt + (long)(n0 + row) * K + k0 + kk, buf + ABUF + c * 8);
      }
    }
  };

  auto compute = [&](const unsigned short* buf) {
    bf16x8 bvv[FN];
#pragma unroll
    for (int fn = 0; fn < FN; ++fn)
      bvv[fn] = *(const bf16x8*)(buf + ABUF + (fn * 16 + fr) * BK + fq * 8);
#pragma unroll
    for (int p = 0; p < P; ++p) {
#pragma unroll
      for (int fm = 0; fm < 2; ++fm) {
        bf16x8 av = *(const bf16x8*)(buf + p * BM * BK + (wv * 32 + fm * 16 + fr) * BK + fq * 8);
#pragma unroll
        for (int fn = 0; fn < FN; ++fn)
          acc[p][fm][fn] =
              __builtin_amdgcn_mfma_f32_16x16x32_bf16(av, bvv[fn], acc[p][fm][fn], 0, 0, 0);
      }
    }
  };

  constexpr int NT = K / BK;
  if constexpr (DBUF) {
    stage(s0, 0);
    asm volatile("s_waitcnt vmcnt(0)" ::: "memory");
    __syncthreads();
    int cur = 0;
#pragma unroll 1
    for (int t = 0; t < NT - 1; ++t) {
      stage(s0 + (cur ^ 1) * BUFE, (t + 1) * BK);
      compute(s0 + cur * BUFE);
      asm volatile("s_waitcnt vmcnt(0)" ::: "memory");
      __syncthreads();
      cur ^= 1;
    }
    compute(s0 + cur * BUFE);
    if constexpr (MODE == 2) __syncthreads();
  } else {
#pragma unroll 1
    for (int t = 0; t < NT; ++t) {
      stage(s0, t * BK);
      asm volatile("s_waitcnt vmcnt(0)" ::: "memory");
      __syncthreads();
      compute(s0);
      __syncthreads();
    }
  }

  if constexpr (MODE == 0) {
    unsigned short* H = (unsigned short*)outp;
#pragma unroll
    for (int fm = 0; fm < 2; ++fm)
#pragma unroll
      for (int fn = 0; fn < FN; ++fn)
#pragma unroll
        for (int r = 0; r < 4; ++r) {
          float vs[P];
          float n2 = 0.f;
#pragma unroll
          for (int p = 0; p < P; ++p) {
            float v = acc[p][fm][fn][r] * sc;
            vs[p] = v;
            n2 += v * v;
          }
          float nm = sqrtf(n2);
          float sg = 1.f / (1.f + __expf(-nm));   // silu(n)/n == sigmoid(n)
          long row = m0 + wv * 32 + fm * 16 + fq * 4 + r;
          int col = n0 + fn * 16 + fr;
#pragma unroll
          for (int p = 0; p < P; ++p)
            H[p * planeOut + row * NN + col] = f2bf(vs[p] * sg);
        }
  } else if constexpr (MODE == 1) {
    float* O = (float*)outp;
#pragma unroll
    for (int fm = 0; fm < 2; ++fm)
#pragma unroll
      for (int fn = 0; fn < FN; ++fn)
#pragma unroll
        for (int r = 0; r < 4; ++r) {
          long row = m0 + wv * 32 + fm * 16 + fq * 4 + r;
          int col = n0 + fn * 16 + fr;
          O[row * 1920 + outOff + col] = acc[0][fm][fn][r] * sc;
        }
  } else {
    float* st = (float*)smem + wv * (16 * BN * P);
    float* O = (float*)outp;
#pragma unroll
    for (int fm = 0; fm < 2; ++fm) {
#pragma unroll
      for (int fn = 0; fn < FN; ++fn)
#pragma unroll
        for (int r = 0; r < 4; ++r)
#pragma unroll
          for (int p = 0; p < P; ++p)
            st[(fq * 4 + r) * BN * P + (fn * 16 + fr) * P + p] = acc[p][fm][fn][r] * sc;
      __syncthreads();
      for (int e = lane; e < 16 * BN * P; e += 64) {
        int rl = e / (BN * P), cc = e - rl * (BN * P);
        long row = m0 + wv * 32 + fm * 16 + rl;
        O[row * 1920 + outOff + n0 * P + cc] = st[e];
      }
      __syncthreads();
    }
  }
}

extern "C" void kernel_launch(void* const* d_in, const int* in_sizes, int n_in,
                              void* d_out, int out_size, void* d_ws, size_t ws_size,
                              hipStream_t stream) {
  const float* x = (const float*)d_in[0];
  const float* w1_0 = (const float*)d_in[1];
  const float* w1_1 = (const float*)d_in[2];
  const float* w1_2 = (const float*)d_in[3];
  const float* w2_0 = (const float*)d_in[4];
  const float* w2_1 = (const float*)d_in[5];
  const float* w2_2 = (const float*)d_in[6];
  float* out = (float*)d_out;

  unsigned short* Xp = (unsigned short*)d_ws;      // N*1920 bf16
  unsigned short* Hp = Xp + NL * 1920;             // N*3840 bf16
  unsigned short* W  = Hp + NL * 3840;             // 1376256 bf16
  unsigned short* Wt1_0 = W;
  unsigned short* Wt1_1 = W + 524288;
  unsigned short* Wt1_2 = W + 655360;
  unsigned short* Wt2_0 = W + 688128;
  unsigned short* Wt2_1 = W + 1212416;
  unsigned short* Wt2_2 = W + 1343488;

  {
    long total = NL * 896 + 1376256;
    prep_kernel<<<dim3((unsigned)((total + 255) / 256)), dim3(256), 0, stream>>>(
        x, w1_0, w1_1, w1_2, w2_0, w2_1, w2_2, Xp, W);
  }

  const float s512 = 0.04419417382f;  // 1/sqrt(512)
  const float s256 = 0.0625f;         // 1/sqrt(256)
  const float s128 = 0.08838834765f;  // 1/sqrt(128)
  const float s1024 = 0.03125f;       // 1/sqrt(1024)

  // Linear1 + NormAct -> Hp planes (bf16)
  gemm_k<1, 128, 512, 1024, 0, 1><<<2048, 256, 32768, stream>>>(
      Xp, 0, Wt1_0, Hp, 0, 0, s512, 8);
  gemm_k<3, 64, 256, 512, 0, 1><<<2048, 256, 57344, stream>>>(
      Xp + NL * 512, NL * 256, Wt1_1, Hp + NL * 1024, NL * 512, 0, s256, 8);
  gemm_k<5, 32, 128, 256, 0, 0><<<2048, 256, 43008, stream>>>(
      Xp + NL * 1280, NL * 128, Wt1_2, Hp + NL * 2560, NL * 256, 0, s128, 8);

  // Linear2 -> out (f32, interleaved layout)
  gemm_k<1, 128, 1024, 512, 1, 1><<<1024, 256, 32768, stream>>>(
      Hp, 0, Wt2_0, out, 0, 0, s1024, 4);
  gemm_k<3, 64, 512, 256, 2, 1><<<1024, 256, 57344, stream>>>(
      Hp + NL * 1024, NL * 512, Wt2_1, out, 0, 512, s512, 4);
  gemm_k<5, 32, 256, 128, 2, 0><<<1024, 256, 43008, stream>>>(
      Hp + NL * 2560, NL * 256, Wt2_2, out, 0, 1280, s256, 4);
}

// Round 3
// 434.644 us; speedup vs baseline: 1.5243x; 1.1599x over previous
//
#include <hip/hip_runtime.h>

#define NL 32768L

typedef __bf16 bf16x8 __attribute__((ext_vector_type(8)));
typedef float f32x4 __attribute__((ext_vector_type(4)));

__device__ __forceinline__ unsigned short f2bf(float f) {
  unsigned int u = __float_as_uint(f);
  u += 0x7FFFu + ((u >> 16) & 1u);   // round-to-nearest-even
  return (unsigned short)(u >> 16);
}

__device__ __forceinline__ void gload16(const void* g, void* l) {
  __builtin_amdgcn_global_load_lds((const __attribute__((address_space(1))) void*)g,
                                   (__attribute__((address_space(3))) void*)l, 16, 0, 0);
}

// ---- combined prep: x -> bf16 d-major planes, weights -> transposed bf16 ----
__global__ void prep_kernel(const float* __restrict__ x,
                            const float* __restrict__ w1_0, const float* __restrict__ w1_1,
                            const float* __restrict__ w1_2, const float* __restrict__ w2_0,
                            const float* __restrict__ w2_1, const float* __restrict__ w2_2,
                            unsigned short* __restrict__ Xp, unsigned short* __restrict__ W) {
  long i = (long)blockIdx.x * blockDim.x + threadIdx.x;
  if (i < NL * 512) {
    long n = i >> 9, u = i & 511;
    Xp[i] = f2bf(x[n * 1920 + u]);
  } else if (i < NL * 768) {
    long j = i - NL * 512;
    long n = j >> 8, u = j & 255;
    const float* s = x + n * 1920 + 512 + u * 3;
    unsigned short* d = Xp + NL * 512 + n * 256 + u;
    d[0]        = f2bf(s[0]);
    d[NL * 256] = f2bf(s[1]);
    d[NL * 512] = f2bf(s[2]);
  } else if (i < NL * 896) {
    long j = i - NL * 768;
    long n = j >> 7, u = j & 127;
    const float* s = x + n * 1920 + 1280 + u * 5;
    unsigned short* d = Xp + NL * 1280 + n * 128 + u;
#pragma unroll
    for (int k = 0; k < 5; ++k) d[k * NL * 128] = f2bf(s[k]);
  } else {
    long j = i - NL * 896;
    if (j < 524288) {            // w1_0: K=512, C=1024
      int c = (int)(j >> 9), r = (int)(j & 511);
      W[j] = f2bf(w1_0[(long)r * 1024 + c]);
    } else if (j < 655360) {     // w1_1: K=256, C=512
      long t = j - 524288; int c = (int)(t >> 8), r = (int)(t & 255);
      W[j] = f2bf(w1_1[(long)r * 512 + c]);
    } else if (j < 688128) {     // w1_2: K=128, C=256
      long t = j - 655360; int c = (int)(t >> 7), r = (int)(t & 127);
      W[j] = f2bf(w1_2[(long)r * 256 + c]);
    } else if (j < 1212416) {    // w2_0: K=1024, C=512
      long t = j - 688128; int c = (int)(t >> 10), r = (int)(t & 1023);
      W[j] = f2bf(w2_0[(long)r * 512 + c]);
    } else if (j < 1343488) {    // w2_1: K=512, C=256
      long t = j - 1212416; int c = (int)(t >> 9), r = (int)(t & 511);
      W[j] = f2bf(w2_1[(long)r * 256 + c]);
    } else if (j < 1376256) {    // w2_2: K=256, C=128
      long t = j - 1343488; int c = (int)(t >> 8), r = (int)(t & 255);
      W[j] = f2bf(w2_2[(long)r * 128 + c]);
    }
  }
}

// ---- plane-batched GEMM v3: counted-vmcnt pipeline --------------------------
// 2x2 wave grid, per-wave (BM/2)x(BN/2) output. NBUF=3: single-barrier 3-buffer
// counted-vmcnt pipeline. NBUF=2: classic 2-phase dbuf (vmcnt(0) per step).
// MODE 0: normact across planes -> bf16 planes (Linear1).
// MODE 1: f32 interleaved direct write out[row*1920 + outOff + col*P + p].
template <int P, int BM, int BN, int K, int NN, int MODE, int NBUF, int MINW>
__global__ __launch_bounds__(256, MINW) void gemm3(
    const unsigned short* __restrict__ Ap, long planeA,
    const unsigned short* __restrict__ Wt,
    void* __restrict__ outp, long planeOut, int outOff, float sc,
    int lognx, int nxm1) {
  constexpr int BK = 32;
  constexpr int FM = BM / 32;             // frags per wave in M
  constexpr int FN = BN / 32;             // frags per wave in N
  constexpr int ACH = P * BM * 4;         // A 16B-chunks per step
  constexpr int BCH = BN * 4;             // B 16B-chunks per step
  constexpr int ITER_A = ACH / 256;
  constexpr int ITER_B = BCH / 256;
  constexpr int ISSUES = ITER_A + ITER_B; // vmcnt events per thread per step
  constexpr int ABUF = P * BM * BK;       // elems
  constexpr int BUFE = ABUF + BN * BK;    // elems per buffer
  constexpr int NT = K / BK;

  extern __shared__ unsigned short sm[];

  const int tid = threadIdx.x;
  const int lane = tid & 63, wv = tid >> 6;
  const int wr = wv >> 1, wc = wv & 1;
  const int fr = lane & 15, fq = lane >> 4;

  const int nwg = gridDim.x, bid = blockIdx.x;
  const int wg = (bid & 7) * (nwg >> 3) + (bid >> 3);   // bijective: nwg % 8 == 0
  const long m0 = (long)(wg >> lognx) * BM;
  const int n0 = (wg & nxm1) * BN;

  f32x4 acc[P][FM][FN];
#pragma unroll
  for (int p = 0; p < P; ++p)
#pragma unroll
    for (int a = 0; a < FM; ++a)
#pragma unroll
      for (int b = 0; b < FN; ++b) acc[p][a][b] = (f32x4){0.f, 0.f, 0.f, 0.f};

  auto stage = [&](unsigned short* buf, int k0) {
#pragma unroll
    for (int it = 0; it < ITER_A; ++it) {
      int c = it * 256 + tid;
      int p = c / (BM * 4);
      int cp = c - p * (BM * 4);
      int row = cp >> 2, kk = (cp & 3) * 8;
      gload16(Ap + (long)p * planeA + (m0 + row) * K + k0 + kk, buf + c * 8);
    }
#pragma unroll
    for (int it = 0; it < ITER_B; ++it) {
      int c = it * 256 + tid;
      int row = c >> 2, kk = (c & 3) * 8;
      gload16(Wt + (long)(n0 + row) * K + k0 + kk, buf + ABUF + c * 8);
    }
  };

  auto compute = [&](const unsigned short* buf) {
    bf16x8 bv[FN];
#pragma unroll
    for (int fn = 0; fn < FN; ++fn)
      bv[fn] = *(const bf16x8*)(buf + ABUF + (wc * (BN / 2) + fn * 16 + fr) * BK + fq * 8);
#pragma unroll
    for (int p = 0; p < P; ++p)
#pragma unroll
      for (int fm = 0; fm < FM; ++fm) {
        bf16x8 av = *(const bf16x8*)(buf + p * BM * BK +
                                     (wr * (BM / 2) + fm * 16 + fr) * BK + fq * 8);
#pragma unroll
        for (int fn = 0; fn < FN; ++fn)
          acc[p][fm][fn] =
              __builtin_amdgcn_mfma_f32_16x16x32_bf16(av, bv[fn], acc[p][fm][fn], 0, 0, 0);
      }
  };

  unsigned short* b0 = sm;
  unsigned short* b1 = sm + BUFE;

  if constexpr (NBUF == 3) {
    unsigned short* b2 = sm + 2 * BUFE;
    stage(b0, 0);
    stage(b1, BK);
#pragma unroll 1
    for (int t = 0; t < NT - 1; ++t) {
      // wait until only the most-recent step's loads are outstanding -> step t landed
      if constexpr (ISSUES == 4) asm volatile("s_waitcnt vmcnt(4)" ::: "memory");
      else if constexpr (ISSUES == 5) asm volatile("s_waitcnt vmcnt(5)" ::: "memory");
      else asm volatile("s_waitcnt vmcnt(6)" ::: "memory");
      __builtin_amdgcn_s_barrier();
      asm volatile("" ::: "memory");        // keep ds_reads below the barrier
      if (t + 2 < NT) stage(b2, (t + 2) * BK);
      compute(b0);
      unsigned short* tmp = b0; b0 = b1; b1 = b2; b2 = tmp;
    }
    asm volatile("s_waitcnt vmcnt(0)" ::: "memory");
    __builtin_amdgcn_s_barrier();
    asm volatile("" ::: "memory");
    compute(b0);
  } else {
    stage(b0, 0);
    asm volatile("s_waitcnt vmcnt(0)" ::: "memory");
    __builtin_amdgcn_s_barrier();
    asm volatile("" ::: "memory");
#pragma unroll 1
    for (int t = 0; t < NT; ++t) {
      if (t + 1 < NT) stage(b1, (t + 1) * BK);
      compute(b0);
      asm volatile("s_waitcnt vmcnt(0)" ::: "memory");
      __builtin_amdgcn_s_barrier();
      asm volatile("" ::: "memory");
      unsigned short* tmp = b0; b0 = b1; b1 = tmp;
    }
  }

  if constexpr (MODE == 0) {
    unsigned short* H = (unsigned short*)outp;
#pragma unroll
    for (int fm = 0; fm < FM; ++fm)
#pragma unroll
      for (int fn = 0; fn < FN; ++fn)
#pragma unroll
        for (int r = 0; r < 4; ++r) {
          float vs[P];
          float n2 = 0.f;
#pragma unroll
          for (int p = 0; p < P; ++p) {
            float v = acc[p][fm][fn][r] * sc;
            vs[p] = v;
            n2 += v * v;
          }
          float nm = sqrtf(n2);
          float sg = 1.f / (1.f + __expf(-nm));   // silu(n)/n == sigmoid(n)
          long row = m0 + wr * (BM / 2) + fm * 16 + fq * 4 + r;
          int col = n0 + wc * (BN / 2) + fn * 16 + fr;
#pragma unroll
          for (int p = 0; p < P; ++p)
            H[p * planeOut + row * NN + col] = f2bf(vs[p] * sg);
        }
  } else {
    float* O = (float*)outp;
#pragma unroll
    for (int fm = 0; fm < FM; ++fm)
#pragma unroll
      for (int fn = 0; fn < FN; ++fn)
#pragma unroll
        for (int r = 0; r < 4; ++r) {
          long row = m0 + wr * (BM / 2) + fm * 16 + fq * 4 + r;
          int col = n0 + wc * (BN / 2) + fn * 16 + fr;
          float* base = O + row * 1920 + outOff + (long)col * P;
#pragma unroll
          for (int p = 0; p < P; ++p) base[p] = acc[p][fm][fn][r] * sc;
        }
  }
}

extern "C" void kernel_launch(void* const* d_in, const int* in_sizes, int n_in,
                              void* d_out, int out_size, void* d_ws, size_t ws_size,
                              hipStream_t stream) {
  const float* x = (const float*)d_in[0];
  const float* w1_0 = (const float*)d_in[1];
  const float* w1_1 = (const float*)d_in[2];
  const float* w1_2 = (const float*)d_in[3];
  const float* w2_0 = (const float*)d_in[4];
  const float* w2_1 = (const float*)d_in[5];
  const float* w2_2 = (const float*)d_in[6];
  float* out = (float*)d_out;

  unsigned short* Xp = (unsigned short*)d_ws;      // N*1920 bf16
  unsigned short* Hp = Xp + NL * 1920;             // N*3840 bf16
  unsigned short* W  = Hp + NL * 3840;             // 1376256 bf16
  unsigned short* Wt1_0 = W;
  unsigned short* Wt1_1 = W + 524288;
  unsigned short* Wt1_2 = W + 655360;
  unsigned short* Wt2_0 = W + 688128;
  unsigned short* Wt2_1 = W + 1212416;
  unsigned short* Wt2_2 = W + 1343488;

  {
    long total = NL * 896 + 1376256;
    prep_kernel<<<dim3((unsigned)((total + 255) / 256)), dim3(256), 0, stream>>>(
        x, w1_0, w1_1, w1_2, w2_0, w2_1, w2_2, Xp, W);
  }

  const float s512 = 0.04419417382f;  // 1/sqrt(512)
  const float s256 = 0.0625f;         // 1/sqrt(256)
  const float s128 = 0.08838834765f;  // 1/sqrt(128)
  const float s1024 = 0.03125f;       // 1/sqrt(1024)

  // Linear1 + NormAct -> Hp planes (bf16)
  gemm3<1, 128, 128, 512, 1024, 0, 3, 3><<<2048, 256, 49152, stream>>>(
      Xp, 0, Wt1_0, Hp, 0, 0, s512, 3, 7);
  gemm3<3, 64, 128, 256, 512, 0, 3, 2><<<2048, 256, 61440, stream>>>(
      Xp + NL * 512, NL * 256, Wt1_1, Hp + NL * 1024, NL * 512, 0, s256, 2, 3);
  gemm3<5, 64, 64, 128, 256, 0, 2, 3><<<2048, 256, 49152, stream>>>(
      Xp + NL * 1280, NL * 128, Wt1_2, Hp + NL * 2560, NL * 256, 0, s128, 2, 3);

  // Linear2 -> out (f32, interleaved layout)
  gemm3<1, 128, 128, 1024, 512, 1, 3, 3><<<1024, 256, 49152, stream>>>(
      Hp, 0, Wt2_0, out, 0, 0, s1024, 2, 3);
  gemm3<3, 64, 128, 512, 256, 1, 3, 2><<<1024, 256, 61440, stream>>>(
      Hp + NL * 1024, NL * 512, Wt2_1, out, 0, 512, s512, 1, 1);
  gemm3<5, 64, 64, 256, 128, 1, 2, 3><<<1024, 256, 49152, stream>>>(
      Hp + NL * 2560, NL * 256, Wt2_2, out, 0, 1280, s256, 1, 1);
}

// Round 4
// 419.706 us; speedup vs baseline: 1.5786x; 1.0356x over previous
//
#include <hip/hip_runtime.h>

#define NL 32768L

typedef __bf16 bf16x8 __attribute__((ext_vector_type(8)));
typedef float f32x4 __attribute__((ext_vector_type(4)));

__device__ __forceinline__ unsigned short f2bf(float f) {
  unsigned int u = __float_as_uint(f);
  u += 0x7FFFu + ((u >> 16) & 1u);   // round-to-nearest-even
  return (unsigned short)(u >> 16);
}

__device__ __forceinline__ void gload16(const void* g, void* l) {
  __builtin_amdgcn_global_load_lds((const __attribute__((address_space(1))) void*)g,
                                   (__attribute__((address_space(3))) void*)l, 16, 0, 0);
}

template <int N>
__device__ __forceinline__ void vmwait() {
  if constexpr (N == 0) asm volatile("s_waitcnt vmcnt(0)" ::: "memory");
  else if constexpr (N == 4) asm volatile("s_waitcnt vmcnt(4)" ::: "memory");
  else if constexpr (N == 5) asm volatile("s_waitcnt vmcnt(5)" ::: "memory");
  else if constexpr (N == 6) asm volatile("s_waitcnt vmcnt(6)" ::: "memory");
  else static_assert(N == 0, "unsupported vmcnt");
}

// ---- combined prep: x -> bf16 d-major planes, weights -> transposed bf16 ----
__global__ void prep_kernel(const float* __restrict__ x,
                            const float* __restrict__ w1_0, const float* __restrict__ w1_1,
                            const float* __restrict__ w1_2, const float* __restrict__ w2_0,
                            const float* __restrict__ w2_1, const float* __restrict__ w2_2,
                            unsigned short* __restrict__ Xp, unsigned short* __restrict__ W) {
  long i = (long)blockIdx.x * blockDim.x + threadIdx.x;
  if (i < NL * 512) {
    long n = i >> 9, u = i & 511;
    Xp[i] = f2bf(x[n * 1920 + u]);
  } else if (i < NL * 768) {
    long j = i - NL * 512;
    long n = j >> 8, u = j & 255;
    const float* s = x + n * 1920 + 512 + u * 3;
    unsigned short* d = Xp + NL * 512 + n * 256 + u;
    d[0]        = f2bf(s[0]);
    d[NL * 256] = f2bf(s[1]);
    d[NL * 512] = f2bf(s[2]);
  } else if (i < NL * 896) {
    long j = i - NL * 768;
    long n = j >> 7, u = j & 127;
    const float* s = x + n * 1920 + 1280 + u * 5;
    unsigned short* d = Xp + NL * 1280 + n * 128 + u;
#pragma unroll
    for (int k = 0; k < 5; ++k) d[k * NL * 128] = f2bf(s[k]);
  } else {
    long j = i - NL * 896;
    if (j < 524288) {            // w1_0: K=512, C=1024
      int c = (int)(j >> 9), r = (int)(j & 511);
      W[j] = f2bf(w1_0[(long)r * 1024 + c]);
    } else if (j < 655360) {     // w1_1: K=256, C=512
      long t = j - 524288; int c = (int)(t >> 8), r = (int)(t & 255);
      W[j] = f2bf(w1_1[(long)r * 512 + c]);
    } else if (j < 688128) {     // w1_2: K=128, C=256
      long t = j - 655360; int c = (int)(t >> 7), r = (int)(t & 127);
      W[j] = f2bf(w1_2[(long)r * 256 + c]);
    } else if (j < 1212416) {    // w2_0: K=1024, C=512
      long t = j - 688128; int c = (int)(t >> 10), r = (int)(t & 1023);
      W[j] = f2bf(w2_0[(long)r * 512 + c]);
    } else if (j < 1343488) {    // w2_1: K=512, C=256
      long t = j - 1212416; int c = (int)(t >> 9), r = (int)(t & 511);
      W[j] = f2bf(w2_1[(long)r * 256 + c]);
    } else if (j < 1376256) {    // w2_2: K=256, C=128
      long t = j - 1343488; int c = (int)(t >> 8), r = (int)(t & 255);
      W[j] = f2bf(w2_2[(long)r * 128 + c]);
    }
  }
}

// ---- counted-vmcnt 3-buffer GEMM core (2x2 waves, BK=32) -------------------
// LDS slot-swizzle: source chunk slot XOR (row&3), same XOR on read (rule 21).
// MODE 0: normact across P planes -> bf16 planes.  MODE 1: f32 interleaved out.
template <int P, int BM, int BN, int K, int NN, int MODE>
__device__ __forceinline__ void gemm_core(
    unsigned short* sm, int b,
    const unsigned short* __restrict__ Ap, long planeA,
    const unsigned short* __restrict__ Wt,
    void* __restrict__ outp, long planeOut, int outOff, float sc) {
  constexpr int BK = 32;
  constexpr int FM = BM / 32, FN = BN / 32;
  constexpr int ITER_A = P * BM / 64;
  constexpr int ITER_B = BN / 64;
  constexpr int ISSUES = ITER_A + ITER_B;
  constexpr int ABUF = P * BM * BK;
  constexpr int BUFE = ABUF + BN * BK;
  constexpr int NT = K / BK;
  constexpr int NX = NN / BN;
  constexpr int NWG = (32768 / BM) * NX;

  const int tid = threadIdx.x;
  const int lane = tid & 63, wv = tid >> 6;
  const int wr = wv >> 1, wc = wv & 1;
  const int fr = lane & 15, fq = lane >> 4;
  const int sw = fr & 3;

  const int wg = (b & 7) * (NWG / 8) + (b >> 3);   // bijective XCD swizzle
  const long m0 = (long)(wg / NX) * BM;
  const int n0 = (wg % NX) * BN;

  f32x4 acc[P][FM][FN];
#pragma unroll
  for (int p = 0; p < P; ++p)
#pragma unroll
    for (int a = 0; a < FM; ++a)
#pragma unroll
      for (int c = 0; c < FN; ++c) acc[p][a][c] = (f32x4){0.f, 0.f, 0.f, 0.f};

  auto stage = [&](unsigned short* buf, int k0) {
#pragma unroll
    for (int it = 0; it < ITER_A; ++it) {
      int c = it * 256 + tid;
      int p = c / (BM * 4);
      int cp = c - p * (BM * 4);
      int row = cp >> 2, sl = cp & 3;
      int kk = (sl ^ (row & 3)) * 8;
      gload16(Ap + (long)p * planeA + (m0 + row) * K + k0 + kk, buf + c * 8);
    }
#pragma unroll
    for (int it = 0; it < ITER_B; ++it) {
      int c = it * 256 + tid;
      int row = c >> 2, sl = c & 3;
      int kk = (sl ^ (row & 3)) * 8;
      gload16(Wt + (long)(n0 + row) * K + k0 + kk, buf + ABUF + c * 8);
    }
  };

  auto compute = [&](const unsigned short* buf) {
    bf16x8 bv[FN];
#pragma unroll
    for (int fn = 0; fn < FN; ++fn) {
      int row = wc * (BN / 2) + fn * 16 + fr;
      bv[fn] = *(const bf16x8*)(buf + ABUF + row * BK + (fq ^ sw) * 8);
    }
#pragma unroll
    for (int p = 0; p < P; ++p)
#pragma unroll
      for (int fm = 0; fm < FM; ++fm) {
        int row = wr * (BM / 2) + fm * 16 + fr;
        bf16x8 av = *(const bf16x8*)(buf + p * BM * BK + row * BK + (fq ^ sw) * 8);
#pragma unroll
        for (int fn = 0; fn < FN; ++fn)
          acc[p][fm][fn] =
              __builtin_amdgcn_mfma_f32_16x16x32_bf16(av, bv[fn], acc[p][fm][fn], 0, 0, 0);
      }
  };

  unsigned short* b0 = sm;
  unsigned short* b1 = sm + BUFE;
  unsigned short* b2 = sm + 2 * BUFE;

  stage(b0, 0);
  stage(b1, BK);
#pragma unroll 1
  for (int t = 0; t < NT - 1; ++t) {
    vmwait<ISSUES>();                    // step-t chunks landed; t+1 stays in flight
    __builtin_amdgcn_s_barrier();
    asm volatile("" ::: "memory");
    if (t + 2 < NT) stage(b2, (t + 2) * BK);
    compute(b0);
    unsigned short* tmp = b0; b0 = b1; b1 = b2; b2 = tmp;
  }
  vmwait<0>();
  __builtin_amdgcn_s_barrier();
  asm volatile("" ::: "memory");
  compute(b0);

  if constexpr (MODE == 0) {
    unsigned short* H = (unsigned short*)outp;
#pragma unroll
    for (int fm = 0; fm < FM; ++fm)
#pragma unroll
      for (int fn = 0; fn < FN; ++fn)
#pragma unroll
        for (int r = 0; r < 4; ++r) {
          float vs[P];
          float n2 = 0.f;
#pragma unroll
          for (int p = 0; p < P; ++p) {
            float v = acc[p][fm][fn][r] * sc;
            vs[p] = v;
            n2 += v * v;
          }
          float nm = sqrtf(n2);
          float sg = 1.f / (1.f + __expf(-nm));   // silu(n)/n == sigmoid(n)
          long row = m0 + wr * (BM / 2) + fm * 16 + fq * 4 + r;
          int col = n0 + wc * (BN / 2) + fn * 16 + fr;
#pragma unroll
          for (int p = 0; p < P; ++p)
            H[p * planeOut + row * NN + col] = f2bf(vs[p] * sg);
        }
  } else {
    float* O = (float*)outp;
#pragma unroll
    for (int fm = 0; fm < FM; ++fm)
#pragma unroll
      for (int fn = 0; fn < FN; ++fn)
#pragma unroll
        for (int r = 0; r < 4; ++r) {
          long row = m0 + wr * (BM / 2) + fm * 16 + fq * 4 + r;
          int col = n0 + wc * (BN / 2) + fn * 16 + fr;
          float* base = O + row * 1920 + outOff + (long)col * P;
#pragma unroll
          for (int p = 0; p < P; ++p) base[p] = acc[p][fm][fn][r] * sc;
        }
  }
}

// ---- full-K single-stage GEMM (for small K): one barrier total -------------
// LDS rows stride K (256B for K=128): slot XOR (row&7) swizzle -> conflict-free.
template <int P, int BM, int BN, int K, int NN, int MODE>
__device__ __forceinline__ void gemm_fullk(
    unsigned short* sm, int b,
    const unsigned short* __restrict__ Ap, long planeA,
    const unsigned short* __restrict__ Wt,
    void* __restrict__ outp, long planeOut, int outOff, float sc) {
  constexpr int FM = BM / 32, FN = BN / 32;
  constexpr int SLOTS = K / 8;                  // 16B chunks per row
  constexpr int ITER_A = P * BM * K / 8 / 256;
  constexpr int ITER_B = BN * K / 8 / 256;
  constexpr int ABUF = P * BM * K;
  constexpr int NX = NN / BN;
  constexpr int NWG = (32768 / BM) * NX;
  constexpr int NKS = K / 32;

  const int tid = threadIdx.x;
  const int lane = tid & 63, wv = tid >> 6;
  const int wr = wv >> 1, wc = wv & 1;
  const int fr = lane & 15, fq = lane >> 4;
  const int sw = fr & 7;

  const int wg = (b & 7) * (NWG / 8) + (b >> 3);
  const long m0 = (long)(wg / NX) * BM;
  const int n0 = (wg % NX) * BN;

  f32x4 acc[P][FM][FN];
#pragma unroll
  for (int p = 0; p < P; ++p)
#pragma unroll
    for (int a = 0; a < FM; ++a)
#pragma unroll
      for (int c = 0; c < FN; ++c) acc[p][a][c] = (f32x4){0.f, 0.f, 0.f, 0.f};

#pragma unroll
  for (int it = 0; it < ITER_A; ++it) {
    int c = it * 256 + tid;
    int p = c / (BM * SLOTS);
    int cp = c - p * (BM * SLOTS);
    int row = cp / SLOTS, sl = cp % SLOTS;
    int kk = (sl ^ (row & 7)) * 8;
    gload16(Ap + (long)p * planeA + (m0 + row) * K + kk, sm + c * 8);
  }
#pragma unroll
  for (int it = 0; it < ITER_B; ++it) {
    int c = it * 256 + tid;
    int row = c / SLOTS, sl = c % SLOTS;
    int kk = (sl ^ (row & 7)) * 8;
    gload16(Wt + (long)(n0 + row) * K + kk, sm + ABUF + c * 8);
  }
  vmwait<0>();
  __builtin_amdgcn_s_barrier();
  asm volatile("" ::: "memory");

#pragma unroll
  for (int ks = 0; ks < NKS; ++ks) {
    bf16x8 bv[FN];
#pragma unroll
    for (int fn = 0; fn < FN; ++fn) {
      int row = wc * (BN / 2) + fn * 16 + fr;
      int sl = (ks * 4 + fq) ^ sw;
      bv[fn] = *(const bf16x8*)(sm + ABUF + row * K + sl * 8);
    }
#pragma unroll
    for (int p = 0; p < P; ++p)
#pragma unroll
      for (int fm = 0; fm < FM; ++fm) {
        int row = wr * (BM / 2) + fm * 16 + fr;
        int sl = (ks * 4 + fq) ^ sw;
        bf16x8 av = *(const bf16x8*)(sm + p * BM * K + row * K + sl * 8);
#pragma unroll
        for (int fn = 0; fn < FN; ++fn)
          acc[p][fm][fn] =
              __builtin_amdgcn_mfma_f32_16x16x32_bf16(av, bv[fn], acc[p][fm][fn], 0, 0, 0);
      }
  }

  if constexpr (MODE == 0) {
    unsigned short* H = (unsigned short*)outp;
#pragma unroll
    for (int fm = 0; fm < FM; ++fm)
#pragma unroll
      for (int fn = 0; fn < FN; ++fn)
#pragma unroll
        for (int r = 0; r < 4; ++r) {
          float vs[P];
          float n2 = 0.f;
#pragma unroll
          for (int p = 0; p < P; ++p) {
            float v = acc[p][fm][fn][r] * sc;
            vs[p] = v;
            n2 += v * v;
          }
          float nm = sqrtf(n2);
          float sg = 1.f / (1.f + __expf(-nm));
          long row = m0 + wr * (BM / 2) + fm * 16 + fq * 4 + r;
          int col = n0 + wc * (BN / 2) + fn * 16 + fr;
#pragma unroll
          for (int p = 0; p < P; ++p)
            H[p * planeOut + row * NN + col] = f2bf(vs[p] * sg);
        }
  } else {
    float* O = (float*)outp;
#pragma unroll
    for (int fm = 0; fm < FM; ++fm)
#pragma unroll
      for (int fn = 0; fn < FN; ++fn)
#pragma unroll
        for (int r = 0; r < 4; ++r) {
          long row = m0 + wr * (BM / 2) + fm * 16 + fq * 4 + r;
          int col = n0 + wc * (BN / 2) + fn * 16 + fr;
          float* base = O + row * 1920 + outOff + (long)col * P;
#pragma unroll
          for (int p = 0; p < P; ++p) base[p] = acc[p][fm][fn][r] * sc;
        }
  }
}

// ---- fat dispatches: route blocks to sub-GEMMs (all subs %8 grid) ----------
__global__ __launch_bounds__(256, 2) void fat1_kernel(
    const unsigned short* __restrict__ Xp, const unsigned short* __restrict__ W,
    unsigned short* __restrict__ Hp) {
  extern __shared__ unsigned short sm[];
  int b = blockIdx.x;
  if (b < 2048) {
    gemm_core<1, 128, 128, 512, 1024, 0>(sm, b, Xp, 0, W, Hp, 0, 0, 0.04419417382f);
  } else if (b < 4096) {
    gemm_core<3, 64, 128, 256, 512, 0>(sm, b - 2048, Xp + NL * 512, NL * 256, W + 524288,
                                       Hp + NL * 1024, NL * 512, 0, 0.0625f);
  } else {
    gemm_fullk<5, 32, 128, 128, 256, 0>(sm, b - 4096, Xp + NL * 1280, NL * 128, W + 655360,
                                        Hp + NL * 2560, NL * 256, 0, 0.08838834765f);
  }
}

__global__ __launch_bounds__(256, 2) void fat2_kernel(
    const unsigned short* __restrict__ Hp, const unsigned short* __restrict__ W,
    float* __restrict__ out) {
  extern __shared__ unsigned short sm[];
  int b = blockIdx.x;
  if (b < 1024) {
    gemm_core<1, 128, 128, 1024, 512, 1>(sm, b, Hp, 0, W + 688128, out, 0, 0, 0.03125f);
  } else if (b < 2048) {
    gemm_core<3, 64, 128, 512, 256, 1>(sm, b - 1024, Hp + NL * 1024, NL * 512, W + 1212416,
                                       out, 0, 512, 0.04419417382f);
  } else {
    gemm_core<5, 64, 64, 256, 128, 1>(sm, b - 2048, Hp + NL * 2560, NL * 256, W + 1343488,
                                      out, 0, 1280, 0.0625f);
  }
}

extern "C" void kernel_launch(void* const* d_in, const int* in_sizes, int n_in,
                              void* d_out, int out_size, void* d_ws, size_t ws_size,
                              hipStream_t stream) {
  const float* x = (const float*)d_in[0];
  const float* w1_0 = (const float*)d_in[1];
  const float* w1_1 = (const float*)d_in[2];
  const float* w1_2 = (const float*)d_in[3];
  const float* w2_0 = (const float*)d_in[4];
  const float* w2_1 = (const float*)d_in[5];
  const float* w2_2 = (const float*)d_in[6];
  float* out = (float*)d_out;

  unsigned short* Xp = (unsigned short*)d_ws;      // N*1920 bf16
  unsigned short* Hp = Xp + NL * 1920;             // N*3840 bf16
  unsigned short* W  = Hp + NL * 3840;             // 1376256 bf16 (all Wt blocks)

  {
    long total = NL * 896 + 1376256;
    prep_kernel<<<dim3((unsigned)((total + 255) / 256)), dim3(256), 0, stream>>>(
        x, w1_0, w1_1, w1_2, w2_0, w2_1, w2_2, Xp, W);
  }

  fat1_kernel<<<6144, 256, 73728, stream>>>(Xp, W, Hp);
  fat2_kernel<<<3072, 256, 73728, stream>>>(Hp, W, out);
}

// Round 5
// 413.810 us; speedup vs baseline: 1.6011x; 1.0142x over previous
//
#include <hip/hip_runtime.h>
#include <hip/hip_bf16.h>

#define NL 32768L

typedef __bf16 bf16x8 __attribute__((ext_vector_type(8)));
typedef float f32x16 __attribute__((ext_vector_type(16)));
typedef float f32x3 __attribute__((ext_vector_type(3)));
typedef float f32x4v __attribute__((ext_vector_type(4)));

__device__ __forceinline__ unsigned short f2bf(float f) {
  unsigned int u = __float_as_uint(f);
  u += 0x7FFFu + ((u >> 16) & 1u);   // round-to-nearest-even
  return (unsigned short)(u >> 16);
}

__device__ __forceinline__ float frcp(float x) {
  float r;
  asm("v_rcp_f32 %0, %1" : "=v"(r) : "v"(x));
  return r;
}

__device__ __forceinline__ void gload16(const void* g, void* l) {
  __builtin_amdgcn_global_load_lds((const __attribute__((address_space(1))) void*)g,
                                   (__attribute__((address_space(3))) void*)l, 16, 0, 0);
}

template <int N>
__device__ __forceinline__ void vmwait() {
  if constexpr (N == 0) asm volatile("s_waitcnt vmcnt(0)" ::: "memory");
  else if constexpr (N == 4) asm volatile("s_waitcnt vmcnt(4)" ::: "memory");
  else if constexpr (N == 5) asm volatile("s_waitcnt vmcnt(5)" ::: "memory");
  else if constexpr (N == 6) asm volatile("s_waitcnt vmcnt(6)" ::: "memory");
  else static_assert(N == 0, "unsupported vmcnt");
}

// ---- combined prep: x -> bf16 d-major planes, weights -> transposed bf16 ----
__global__ void prep_kernel(const float* __restrict__ x,
                            const float* __restrict__ w1_0, const float* __restrict__ w1_1,
                            const float* __restrict__ w1_2, const float* __restrict__ w2_0,
                            const float* __restrict__ w2_1, const float* __restrict__ w2_2,
                            unsigned short* __restrict__ Xp, unsigned short* __restrict__ W) {
  long i = (long)blockIdx.x * blockDim.x + threadIdx.x;
  if (i < NL * 512) {
    long n = i >> 9, u = i & 511;
    Xp[i] = f2bf(x[n * 1920 + u]);
  } else if (i < NL * 768) {
    long j = i - NL * 512;
    long n = j >> 8, u = j & 255;
    const float* s = x + n * 1920 + 512 + u * 3;
    unsigned short* d = Xp + NL * 512 + n * 256 + u;
    d[0]        = f2bf(s[0]);
    d[NL * 256] = f2bf(s[1]);
    d[NL * 512] = f2bf(s[2]);
  } else if (i < NL * 896) {
    long j = i - NL * 768;
    long n = j >> 7, u = j & 127;
    const float* s = x + n * 1920 + 1280 + u * 5;
    unsigned short* d = Xp + NL * 1280 + n * 128 + u;
#pragma unroll
    for (int k = 0; k < 5; ++k) d[k * NL * 128] = f2bf(s[k]);
  } else {
    long j = i - NL * 896;
    if (j < 524288) {            // w1_0: K=512, C=1024
      int c = (int)(j >> 9), r = (int)(j & 511);
      W[j] = f2bf(w1_0[(long)r * 1024 + c]);
    } else if (j < 655360) {     // w1_1: K=256, C=512
      long t = j - 524288; int c = (int)(t >> 8), r = (int)(t & 255);
      W[j] = f2bf(w1_1[(long)r * 512 + c]);
    } else if (j < 688128) {     // w1_2: K=128, C=256
      long t = j - 655360; int c = (int)(t >> 7), r = (int)(t & 127);
      W[j] = f2bf(w1_2[(long)r * 256 + c]);
    } else if (j < 1212416) {    // w2_0: K=1024, C=512
      long t = j - 688128; int c = (int)(t >> 10), r = (int)(t & 1023);
      W[j] = f2bf(w2_0[(long)r * 512 + c]);
    } else if (j < 1343488) {    // w2_1: K=512, C=256
      long t = j - 1212416; int c = (int)(t >> 9), r = (int)(t & 511);
      W[j] = f2bf(w2_1[(long)r * 256 + c]);
    } else if (j < 1376256) {    // w2_2: K=256, C=128
      long t = j - 1343488; int c = (int)(t >> 8), r = (int)(t & 255);
      W[j] = f2bf(w2_2[(long)r * 128 + c]);
    }
  }
}

// ---- GEMM core: 32x32x16 MFMA, 2x2 waves, BK=32, fully unrolled K ---------
// NBUF=3: counted-vmcnt depth-2 pipeline. NBUF=2: dbuf, stage-before-compute.
// Bank swizzle rank-8: slot ^= (row>>1)&3 on BOTH gload source and ds_read.
// MODE 0: normact across P planes -> bf16 planes.  MODE 1: f32 interleaved out.
template <int P, int BM, int BN, int K, int NN, int MODE, int NBUF>
__device__ __forceinline__ void gemm_core(
    unsigned short* sm, int b,
    const unsigned short* __restrict__ Ap, long planeA,
    const unsigned short* __restrict__ Wt,
    void* __restrict__ outp, long planeOut, int outOff, float sc) {
  constexpr int BK = 32;
  constexpr int FM = BM / 64, FN = BN / 64;      // 32x32 frags per wave
  constexpr int ITER_A = P * BM / 64;
  constexpr int ITER_B = BN / 64;
  constexpr int ISSUES = ITER_A + ITER_B;
  constexpr int ABUF = P * BM * BK;
  constexpr int BUFE = ABUF + BN * BK;
  constexpr int NT = K / BK;
  constexpr int NX = NN / BN;
  constexpr int NWG = (32768 / BM) * NX;

  const int tid = threadIdx.x;
  const int lane = tid & 63, wv = tid >> 6;
  const int wr = wv >> 1, wc = wv & 1;
  const int ln31 = lane & 31, kh = lane >> 5;

  const int wg = (b & 7) * (NWG / 8) + (b >> 3);   // bijective XCD swizzle
  const long m0 = (long)(wg / NX) * BM;
  const int n0 = (wg % NX) * BN;

  f32x16 acc[P][FM][FN];
#pragma unroll
  for (int p = 0; p < P; ++p)
#pragma unroll
    for (int a = 0; a < FM; ++a)
#pragma unroll
      for (int c = 0; c < FN; ++c) acc[p][a][c] = (f32x16)0.f;

  auto stage = [&](int bi, int t) {
    unsigned short* buf = sm + bi * BUFE;
#pragma unroll
    for (int it = 0; it < ITER_A; ++it) {
      int c = it * 256 + tid;
      int p = c / (BM * 4);
      int cp = c - p * (BM * 4);
      int row = cp >> 2, sl = cp & 3;
      int slp = sl ^ ((row >> 1) & 3);
      gload16(Ap + (long)p * planeA + (m0 + row) * K + t * BK + slp * 8, buf + c * 8);
    }
#pragma unroll
    for (int it = 0; it < ITER_B; ++it) {
      int c = it * 256 + tid;
      int row = c >> 2, sl = c & 3;
      int slp = sl ^ ((row >> 1) & 3);
      gload16(Wt + (long)(n0 + row) * K + t * BK + slp * 8, buf + ABUF + c * 8);
    }
  };

  auto compute = [&](int bi) {
    const unsigned short* buf = sm + bi * BUFE;
    bf16x8 bv[FN][2];
#pragma unroll
    for (int fn = 0; fn < FN; ++fn)
#pragma unroll
      for (int ks = 0; ks < 2; ++ks) {
        int row = wc * (BN / 2) + fn * 32 + ln31;
        int slot = (ks * 2 + kh) ^ ((row >> 1) & 3);
        bv[fn][ks] = *(const bf16x8*)(buf + ABUF + row * BK + slot * 8);
      }
    bf16x8 av[P][FM][2];
#pragma unroll
    for (int p = 0; p < P; ++p)
#pragma unroll
      for (int fm = 0; fm < FM; ++fm)
#pragma unroll
        for (int ks = 0; ks < 2; ++ks) {
          int row = wr * (BM / 2) + fm * 32 + ln31;
          int slot = (ks * 2 + kh) ^ ((row >> 1) & 3);
          av[p][fm][ks] = *(const bf16x8*)(buf + p * BM * BK + row * BK + slot * 8);
        }
    __builtin_amdgcn_s_setprio(1);
#pragma unroll
    for (int p = 0; p < P; ++p)
#pragma unroll
      for (int fm = 0; fm < FM; ++fm)
#pragma unroll
        for (int fn = 0; fn < FN; ++fn)
#pragma unroll
          for (int ks = 0; ks < 2; ++ks)
            acc[p][fm][fn] = __builtin_amdgcn_mfma_f32_32x32x16_bf16(
                av[p][fm][ks], bv[fn][ks], acc[p][fm][fn], 0, 0, 0);
    __builtin_amdgcn_s_setprio(0);
  };

  if constexpr (NBUF == 3) {
    stage(0, 0);
    stage(1, 1);
#pragma unroll
    for (int t = 0; t < NT; ++t) {
      if (t < NT - 1) vmwait<ISSUES>(); else vmwait<0>();
      __builtin_amdgcn_s_barrier();
      asm volatile("" ::: "memory");
      if (t + 2 < NT) stage((t + 2) % 3, t + 2);
      compute(t % 3);
    }
  } else {
    stage(0, 0);
    vmwait<0>();
    __builtin_amdgcn_s_barrier();
    asm volatile("" ::: "memory");
#pragma unroll
    for (int t = 0; t < NT; ++t) {
      if (t + 1 < NT) stage((t + 1) & 1, t + 1);
      compute(t & 1);
      if (t + 1 < NT) {
        vmwait<0>();
        __builtin_amdgcn_s_barrier();
        asm volatile("" ::: "memory");
      }
    }
  }

  if constexpr (MODE == 0) {
    __hip_bfloat16* H = (__hip_bfloat16*)outp;
#pragma unroll
    for (int fm = 0; fm < FM; ++fm)
#pragma unroll
      for (int fn = 0; fn < FN; ++fn)
#pragma unroll
        for (int reg = 0; reg < 16; ++reg) {
          long row = m0 + wr * (BM / 2) + fm * 32 + (reg & 3) + 8 * (reg >> 2) + 4 * kh;
          int col = n0 + wc * (BN / 2) + fn * 32 + ln31;
          float vs[P];
          float n2 = 0.f;
#pragma unroll
          for (int p = 0; p < P; ++p) {
            float v = acc[p][fm][fn][reg] * sc;
            vs[p] = v;
            n2 += v * v;
          }
          float nm = (P == 1) ? fabsf(vs[0]) : sqrtf(n2);
          float sg = frcp(1.f + __expf(-nm));   // silu(n)/n == sigmoid(n)
#pragma unroll
          for (int p = 0; p < P; ++p)
            H[p * planeOut + row * NN + col] = __float2bfloat16(vs[p] * sg);
        }
  } else {
    float* O = (float*)outp;
#pragma unroll
    for (int fm = 0; fm < FM; ++fm)
#pragma unroll
      for (int fn = 0; fn < FN; ++fn)
#pragma unroll
        for (int reg = 0; reg < 16; ++reg) {
          long row = m0 + wr * (BM / 2) + fm * 32 + (reg & 3) + 8 * (reg >> 2) + 4 * kh;
          int col = n0 + wc * (BN / 2) + fn * 32 + ln31;
          float* base = O + row * 1920 + outOff + (long)col * P;
          if constexpr (P == 1) {
            base[0] = acc[0][fm][fn][reg] * sc;
          } else if constexpr (P == 3) {
            f32x3 v3;
#pragma unroll
            for (int p = 0; p < 3; ++p) v3[p] = acc[p][fm][fn][reg] * sc;
            *(f32x3*)base = v3;
          } else {
            f32x4v v4;
#pragma unroll
            for (int p = 0; p < 4; ++p) v4[p] = acc[p][fm][fn][reg] * sc;
            *(f32x4v*)base = v4;
            base[4] = acc[4][fm][fn][reg] * sc;
          }
        }
  }
}

// ---- fat dispatches --------------------------------------------------------
__global__ __launch_bounds__(256, 3) void fat1_kernel(
    const unsigned short* __restrict__ Xp, const unsigned short* __restrict__ W,
    unsigned short* __restrict__ Hp) {
  extern __shared__ unsigned short sm[];
  int b = blockIdx.x;
  if (b < 2048) {
    gemm_core<1, 128, 128, 512, 1024, 0, 3>(sm, b, Xp, 0, W, Hp, 0, 0, 0.04419417382f);
  } else if (b < 4096) {
    gemm_core<3, 64, 128, 256, 512, 0, 2>(sm, b - 2048, Xp + NL * 512, NL * 256, W + 524288,
                                          Hp + NL * 1024, NL * 512, 0, 0.0625f);
  } else {
    gemm_core<5, 64, 64, 128, 256, 0, 2>(sm, b - 4096, Xp + NL * 1280, NL * 128, W + 655360,
                                         Hp + NL * 2560, NL * 256, 0, 0.08838834765f);
  }
}

__global__ __launch_bounds__(256, 3) void fat2_kernel(
    const unsigned short* __restrict__ Hp, const unsigned short* __restrict__ W,
    float* __restrict__ out) {
  extern __shared__ unsigned short sm[];
  int b = blockIdx.x;
  if (b < 1024) {
    gemm_core<1, 128, 128, 1024, 512, 1, 3>(sm, b, Hp, 0, W + 688128, out, 0, 0, 0.03125f);
  } else if (b < 2048) {
    gemm_core<3, 64, 128, 512, 256, 1, 2>(sm, b - 1024, Hp + NL * 1024, NL * 512, W + 1212416,
                                          out, 0, 512, 0.04419417382f);
  } else {
    gemm_core<5, 64, 64, 256, 128, 1, 2>(sm, b - 2048, Hp + NL * 2560, NL * 256, W + 1343488,
                                         out, 0, 1280, 0.0625f);
  }
}

extern "C" void kernel_launch(void* const* d_in, const int* in_sizes, int n_in,
                              void* d_out, int out_size, void* d_ws, size_t ws_size,
                              hipStream_t stream) {
  const float* x = (const float*)d_in[0];
  const float* w1_0 = (const float*)d_in[1];
  const float* w1_1 = (const float*)d_in[2];
  const float* w1_2 = (const float*)d_in[3];
  const float* w2_0 = (const float*)d_in[4];
  const float* w2_1 = (const float*)d_in[5];
  const float* w2_2 = (const float*)d_in[6];
  float* out = (float*)d_out;

  unsigned short* Xp = (unsigned short*)d_ws;      // N*1920 bf16
  unsigned short* Hp = Xp + NL * 1920;             // N*3840 bf16
  unsigned short* W  = Hp + NL * 3840;             // 1376256 bf16 (all Wt blocks)

  {
    long total = NL * 896 + 1376256;
    prep_kernel<<<dim3((unsigned)((total + 255) / 256)), dim3(256), 0, stream>>>(
        x, w1_0, w1_1, w1_2, w2_0, w2_1, w2_2, Xp, W);
  }

  fat1_kernel<<<6144, 256, 49152, stream>>>(Xp, W, Hp);
  fat2_kernel<<<3072, 256, 49152, stream>>>(Hp, W, out);
}

// Round 6
// 385.983 us; speedup vs baseline: 1.7165x; 1.0721x over previous
//
#include <hip/hip_runtime.h>
#include <hip/hip_bf16.h>

#define NL 32768L

typedef __bf16 bf16x8 __attribute__((ext_vector_type(8)));
typedef float f32x16 __attribute__((ext_vector_type(16)));
typedef float f32x3 __attribute__((ext_vector_type(3)));
typedef float f32x4v __attribute__((ext_vector_type(4)));

__device__ __forceinline__ unsigned short f2bf(float f) {
  unsigned int u = __float_as_uint(f);
  u += 0x7FFFu + ((u >> 16) & 1u);   // round-to-nearest-even
  return (unsigned short)(u >> 16);
}

__device__ __forceinline__ float frcp(float x) {
  float r;
  asm("v_rcp_f32 %0, %1" : "=v"(r) : "v"(x));
  return r;
}

__device__ __forceinline__ void gload16(const void* g, void* l) {
  __builtin_amdgcn_global_load_lds((const __attribute__((address_space(1))) void*)g,
                                   (__attribute__((address_space(3))) void*)l, 16, 0, 0);
}

__device__ __forceinline__ void vmwait0() {
  asm volatile("s_waitcnt vmcnt(0)" ::: "memory");
}

// ---- combined prep: x -> bf16 d-major planes, weights -> transposed bf16 ----
__global__ void prep_kernel(const float* __restrict__ x,
                            const float* __restrict__ w1_0, const float* __restrict__ w1_1,
                            const float* __restrict__ w1_2, const float* __restrict__ w2_0,
                            const float* __restrict__ w2_1, const float* __restrict__ w2_2,
                            unsigned short* __restrict__ Xp, unsigned short* __restrict__ W) {
  long i = (long)blockIdx.x * blockDim.x + threadIdx.x;
  if (i < NL * 512) {
    long n = i >> 9, u = i & 511;
    Xp[i] = f2bf(x[n * 1920 + u]);
  } else if (i < NL * 768) {
    long j = i - NL * 512;
    long n = j >> 8, u = j & 255;
    const float* s = x + n * 1920 + 512 + u * 3;
    unsigned short* d = Xp + NL * 512 + n * 256 + u;
    d[0]        = f2bf(s[0]);
    d[NL * 256] = f2bf(s[1]);
    d[NL * 512] = f2bf(s[2]);
  } else if (i < NL * 896) {
    long j = i - NL * 768;
    long n = j >> 7, u = j & 127;
    const float* s = x + n * 1920 + 1280 + u * 5;
    unsigned short* d = Xp + NL * 1280 + n * 128 + u;
#pragma unroll
    for (int k = 0; k < 5; ++k) d[k * NL * 128] = f2bf(s[k]);
  } else {
    long j = i - NL * 896;
    if (j < 524288) {            // w1_0: K=512, C=1024
      int c = (int)(j >> 9), r = (int)(j & 511);
      W[j] = f2bf(w1_0[(long)r * 1024 + c]);
    } else if (j < 655360) {     // w1_1: K=256, C=512
      long t = j - 524288; int c = (int)(t >> 8), r = (int)(t & 255);
      W[j] = f2bf(w1_1[(long)r * 512 + c]);
    } else if (j < 688128) {     // w1_2: K=128, C=256
      long t = j - 655360; int c = (int)(t >> 7), r = (int)(t & 127);
      W[j] = f2bf(w1_2[(long)r * 256 + c]);
    } else if (j < 1212416) {    // w2_0: K=1024, C=512
      long t = j - 688128; int c = (int)(t >> 10), r = (int)(t & 1023);
      W[j] = f2bf(w2_0[(long)r * 512 + c]);
    } else if (j < 1343488) {    // w2_1: K=512, C=256
      long t = j - 1212416; int c = (int)(t >> 9), r = (int)(t & 511);
      W[j] = f2bf(w2_1[(long)r * 256 + c]);
    } else if (j < 1376256) {    // w2_2: K=256, C=128
      long t = j - 1343488; int c = (int)(t >> 8), r = (int)(t & 255);
      W[j] = f2bf(w2_2[(long)r * 128 + c]);
    }
  }
}

// ---- GEMM core: 512 thr, WM x WN waves, 32x32x16 MFMA, BK=64, 2-buf --------
// Schedule (guide T3-minimum): {STAGE(next); compute(cur); vmcnt(0); barrier}.
// Bank swizzle: 16B slot ^= (row>>1)&7 on BOTH gload source and ds_read.
// MODE 0: normact across P planes -> bf16 planes.  MODE 1: f32 interleaved out.
template <int P, int BM, int BN, int K, int NN, int MODE, int WM, int WN>
__device__ __forceinline__ void gemm_core(
    unsigned short* sm, int b,
    const unsigned short* __restrict__ Ap, long planeA,
    const unsigned short* __restrict__ Wt,
    void* __restrict__ outp, long planeOut, int outOff, float sc) {
  constexpr int BK = 64;
  constexpr int RM = BM / WM, RN = BN / WN;     // per-wave tile
  constexpr int FM = RM / 32, FN = RN / 32;
  constexpr int ACH = P * BM * 8;               // 16B chunks per A stage
  constexpr int TC = ACH + BN * 8;
  constexpr int FULL = TC / 512;
  static_assert(TC % 512 == 0, "chunks must be uniform");
  constexpr int ABUF = P * BM * BK;             // elems
  constexpr int BUFE = ABUF + BN * BK;
  constexpr int NT = K / BK;
  constexpr int NX = NN / BN;
  constexpr int NWG = (32768 / BM) * NX;

  const int tid = threadIdx.x;
  const int lane = tid & 63, wv = tid >> 6;
  const int wr = wv / WN, wc = wv % WN;
  const int ln31 = lane & 31, kh = lane >> 5;

  const int wg = (b & 7) * (NWG / 8) + (b >> 3);   // bijective XCD swizzle
  const long m0 = (long)(wg / NX) * BM;
  const int n0 = (wg % NX) * BN;

  f32x16 acc[P][FM][FN];
#pragma unroll
  for (int p = 0; p < P; ++p)
#pragma unroll
    for (int a = 0; a < FM; ++a)
#pragma unroll
      for (int c = 0; c < FN; ++c) acc[p][a][c] = (f32x16)0.f;

  auto stage = [&](unsigned short* buf, int t) {
#pragma unroll
    for (int it = 0; it < FULL; ++it) {
      int c = it * 512 + tid;
      if (c < ACH) {                     // constant per unrolled it (ACH%512==0)
        int p = c / (BM * 8);
        int cp = c - p * (BM * 8);
        int row = cp >> 3, sl = cp & 7;
        int slp = sl ^ ((row >> 1) & 7);
        gload16(Ap + (long)p * planeA + (m0 + row) * K + t * BK + slp * 8, buf + c * 8);
      } else {
        int cb = c - ACH;
        int row = cb >> 3, sl = cb & 7;
        int slp = sl ^ ((row >> 1) & 7);
        gload16(Wt + (long)(n0 + row) * K + t * BK + slp * 8, buf + ABUF + cb * 8);
      }
    }
  };

  auto compute = [&](const unsigned short* buf) {
#pragma unroll
    for (int ks = 0; ks < 4; ++ks) {
      bf16x8 bv[FN];
#pragma unroll
      for (int fn = 0; fn < FN; ++fn) {
        int row = wc * RN + fn * 32 + ln31;
        int s = (ks * 2 + kh) ^ ((row >> 1) & 7);
        bv[fn] = *(const bf16x8*)(buf + ABUF + row * BK + s * 8);
      }
      bf16x8 av[P][FM];
#pragma unroll
      for (int p = 0; p < P; ++p)
#pragma unroll
        for (int fm = 0; fm < FM; ++fm) {
          int row = wr * RM + fm * 32 + ln31;
          int s = (ks * 2 + kh) ^ ((row >> 1) & 7);
          av[p][fm] = *(const bf16x8*)(buf + p * BM * BK + row * BK + s * 8);
        }
      __builtin_amdgcn_s_setprio(1);
#pragma unroll
      for (int p = 0; p < P; ++p)
#pragma unroll
        for (int fm = 0; fm < FM; ++fm)
#pragma unroll
          for (int fn = 0; fn < FN; ++fn)
            acc[p][fm][fn] = __builtin_amdgcn_mfma_f32_32x32x16_bf16(
                av[p][fm], bv[fn], acc[p][fm][fn], 0, 0, 0);
      __builtin_amdgcn_s_setprio(0);
    }
  };

  stage(sm, 0);
  vmwait0();
  __builtin_amdgcn_s_barrier();
  asm volatile("" ::: "memory");
#pragma unroll
  for (int t = 0; t < NT; ++t) {
    if (t + 1 < NT) stage(sm + ((t + 1) & 1) * BUFE, t + 1);
    compute(sm + (t & 1) * BUFE);
    if (t + 1 < NT) {
      vmwait0();
      __builtin_amdgcn_s_barrier();
      asm volatile("" ::: "memory");
    }
  }

  if constexpr (MODE == 0) {
    __hip_bfloat16* H = (__hip_bfloat16*)outp;
#pragma unroll
    for (int fm = 0; fm < FM; ++fm)
#pragma unroll
      for (int fn = 0; fn < FN; ++fn)
#pragma unroll
        for (int reg = 0; reg < 16; ++reg) {
          long row = m0 + wr * RM + fm * 32 + (reg & 3) + 8 * (reg >> 2) + 4 * kh;
          int col = n0 + wc * RN + fn * 32 + ln31;
          float vs[P];
          float n2 = 0.f;
#pragma unroll
          for (int p = 0; p < P; ++p) {
            float v = acc[p][fm][fn][reg] * sc;
            vs[p] = v;
            n2 += v * v;
          }
          float nm = (P == 1) ? fabsf(vs[0]) : sqrtf(n2);
          float sg = frcp(1.f + __expf(-nm));   // silu(n)/n == sigmoid(n)
#pragma unroll
          for (int p = 0; p < P; ++p)
            H[p * planeOut + row * NN + col] = __float2bfloat16(vs[p] * sg);
        }
  } else {
    float* O = (float*)outp;
#pragma unroll
    for (int fm = 0; fm < FM; ++fm)
#pragma unroll
      for (int fn = 0; fn < FN; ++fn)
#pragma unroll
        for (int reg = 0; reg < 16; ++reg) {
          long row = m0 + wr * RM + fm * 32 + (reg & 3) + 8 * (reg >> 2) + 4 * kh;
          int col = n0 + wc * RN + fn * 32 + ln31;
          float* base = O + row * 1920 + outOff + (long)col * P;
          if constexpr (P == 1) {
            base[0] = acc[0][fm][fn][reg] * sc;
          } else if constexpr (P == 3) {
            f32x3 v3;
#pragma unroll
            for (int p = 0; p < 3; ++p) v3[p] = acc[p][fm][fn][reg] * sc;
            *(f32x3*)base = v3;
          } else {
            f32x4v v4;
#pragma unroll
            for (int p = 0; p < 4; ++p) v4[p] = acc[p][fm][fn][reg] * sc;
            *(f32x4v*)base = v4;
            base[4] = acc[4][fm][fn][reg] * sc;
          }
        }
  }
}

// ---- fat dispatches (512 threads; longest sub-GEMM first) ------------------
__global__ __launch_bounds__(512, 2) void fat1_kernel(
    const unsigned short* __restrict__ Xp, const unsigned short* __restrict__ W,
    unsigned short* __restrict__ Hp) {
  extern __shared__ unsigned short sm[];
  int b = blockIdx.x;
  if (b < 512) {        // l0: 256x256 tile, K=512
    gemm_core<1, 256, 256, 512, 1024, 0, 2, 4>(sm, b, Xp, 0, W, Hp, 0, 0, 0.04419417382f);
  } else if (b < 1536) { // l1: P=3, 64x256, K=256
    gemm_core<3, 64, 256, 256, 512, 0, 2, 4>(sm, b - 512, Xp + NL * 512, NL * 256, W + 524288,
                                             Hp + NL * 1024, NL * 512, 0, 0.0625f);
  } else {              // l2: P=5, 64x128, K=128
    gemm_core<5, 64, 128, 128, 256, 0, 2, 4>(sm, b - 1536, Xp + NL * 1280, NL * 128, W + 655360,
                                             Hp + NL * 2560, NL * 256, 0, 0.08838834765f);
  }
}

__global__ __launch_bounds__(512, 2) void fat2_kernel(
    const unsigned short* __restrict__ Hp, const unsigned short* __restrict__ W,
    float* __restrict__ out) {
  extern __shared__ unsigned short sm[];
  int b = blockIdx.x;
  if (b < 256) {        // l0: 256x256, K=1024
    gemm_core<1, 256, 256, 1024, 512, 1, 2, 4>(sm, b, Hp, 0, W + 688128, out, 0, 0, 0.03125f);
  } else if (b < 768) { // l1: P=3, 64x256, K=512
    gemm_core<3, 64, 256, 512, 256, 1, 2, 4>(sm, b - 256, Hp + NL * 1024, NL * 512, W + 1212416,
                                             out, 0, 512, 0.04419417382f);
  } else {              // l2: P=5, 64x128, K=256
    gemm_core<5, 64, 128, 256, 128, 1, 2, 4>(sm, b - 768, Hp + NL * 2560, NL * 256, W + 1343488,
                                             out, 0, 1280, 0.0625f);
  }
}

extern "C" void kernel_launch(void* const* d_in, const int* in_sizes, int n_in,
                              void* d_out, int out_size, void* d_ws, size_t ws_size,
                              hipStream_t stream) {
  const float* x = (const float*)d_in[0];
  const float* w1_0 = (const float*)d_in[1];
  const float* w1_1 = (const float*)d_in[2];
  const float* w1_2 = (const float*)d_in[3];
  const float* w2_0 = (const float*)d_in[4];
  const float* w2_1 = (const float*)d_in[5];
  const float* w2_2 = (const float*)d_in[6];
  float* out = (float*)d_out;

  unsigned short* Xp = (unsigned short*)d_ws;      // N*1920 bf16
  unsigned short* Hp = Xp + NL * 1920;             // N*3840 bf16
  unsigned short* W  = Hp + NL * 3840;             // 1376256 bf16 (all Wt blocks)

  {
    long total = NL * 896 + 1376256;
    prep_kernel<<<dim3((unsigned)((total + 255) / 256)), dim3(256), 0, stream>>>(
        x, w1_0, w1_1, w1_2, w2_0, w2_1, w2_2, Xp, W);
  }

  // LDS: l0 core 2 x (256+256)*64*2B = 128 KiB (max across branches)
  fat1_kernel<<<2560, 512, 131072, stream>>>(Xp, W, Hp);
  fat2_kernel<<<1280, 512, 131072, stream>>>(Hp, W, out);
}

// Round 7
// 382.043 us; speedup vs baseline: 1.7342x; 1.0103x over previous
//
#include <hip/hip_runtime.h>
#include <hip/hip_bf16.h>

#define NL 32768L

typedef __bf16 bf16x8 __attribute__((ext_vector_type(8)));
typedef float f32x16 __attribute__((ext_vector_type(16)));
typedef float f32x3 __attribute__((ext_vector_type(3)));
typedef float f32x4v __attribute__((ext_vector_type(4)));

__device__ __forceinline__ unsigned short f2bf(float f) {
  unsigned int u = __float_as_uint(f);
  u += 0x7FFFu + ((u >> 16) & 1u);   // round-to-nearest-even
  return (unsigned short)(u >> 16);
}

__device__ __forceinline__ float frcp(float x) {
  float r;
  asm("v_rcp_f32 %0, %1" : "=v"(r) : "v"(x));
  return r;
}

__device__ __forceinline__ void gload16(const void* g, void* l) {
  __builtin_amdgcn_global_load_lds((const __attribute__((address_space(1))) void*)g,
                                   (__attribute__((address_space(3))) void*)l, 16, 0, 0);
}

template <int N>
__device__ __forceinline__ void vmwait() {
  if constexpr (N == 0) asm volatile("s_waitcnt vmcnt(0)" ::: "memory");
  else if constexpr (N == 4) asm volatile("s_waitcnt vmcnt(4)" ::: "memory");
  else static_assert(N == 0, "unsupported vmcnt");
}

// ---- combined prep: x -> bf16 d-major planes, weights -> transposed bf16 ----
__global__ void prep_kernel(const float* __restrict__ x,
                            const float* __restrict__ w1_0, const float* __restrict__ w1_1,
                            const float* __restrict__ w1_2, const float* __restrict__ w2_0,
                            const float* __restrict__ w2_1, const float* __restrict__ w2_2,
                            unsigned short* __restrict__ Xp, unsigned short* __restrict__ W) {
  long i = (long)blockIdx.x * blockDim.x + threadIdx.x;
  if (i < NL * 512) {
    long n = i >> 9, u = i & 511;
    Xp[i] = f2bf(x[n * 1920 + u]);
  } else if (i < NL * 768) {
    long j = i - NL * 512;
    long n = j >> 8, u = j & 255;
    const float* s = x + n * 1920 + 512 + u * 3;
    unsigned short* d = Xp + NL * 512 + n * 256 + u;
    d[0]        = f2bf(s[0]);
    d[NL * 256] = f2bf(s[1]);
    d[NL * 512] = f2bf(s[2]);
  } else if (i < NL * 896) {
    long j = i - NL * 768;
    long n = j >> 7, u = j & 127;
    const float* s = x + n * 1920 + 1280 + u * 5;
    unsigned short* d = Xp + NL * 1280 + n * 128 + u;
#pragma unroll
    for (int k = 0; k < 5; ++k) d[k * NL * 128] = f2bf(s[k]);
  } else {
    long j = i - NL * 896;
    if (j < 524288) {            // w1_0: K=512, C=1024
      int c = (int)(j >> 9), r = (int)(j & 511);
      W[j] = f2bf(w1_0[(long)r * 1024 + c]);
    } else if (j < 655360) {     // w1_1: K=256, C=512
      long t = j - 524288; int c = (int)(t >> 8), r = (int)(t & 255);
      W[j] = f2bf(w1_1[(long)r * 512 + c]);
    } else if (j < 688128) {     // w1_2: K=128, C=256
      long t = j - 655360; int c = (int)(t >> 7), r = (int)(t & 127);
      W[j] = f2bf(w1_2[(long)r * 256 + c]);
    } else if (j < 1212416) {    // w2_0: K=1024, C=512
      long t = j - 688128; int c = (int)(t >> 10), r = (int)(t & 1023);
      W[j] = f2bf(w2_0[(long)r * 512 + c]);
    } else if (j < 1343488) {    // w2_1: K=512, C=256
      long t = j - 1212416; int c = (int)(t >> 9), r = (int)(t & 511);
      W[j] = f2bf(w2_1[(long)r * 256 + c]);
    } else if (j < 1376256) {    // w2_2: K=256, C=128
      long t = j - 1343488; int c = (int)(t >> 8), r = (int)(t & 255);
      W[j] = f2bf(w2_2[(long)r * 128 + c]);
    }
  }
}

// ---- GEMM core: 512 thr, counted-vmcnt 3-sub-buffer pipeline, BK2=32 -------
// Schedule (r4-proven): {vmcnt(ISSUES); barrier; stage(t+2 -> buf[(t+2)%3]);
// compute(buf[t%3])}. Loads for t+1/t+2 stay in flight across the barrier.
// Bank swizzle: 16B slot ^= (row>>1)&3 on BOTH gload source and ds_read.
// MODE 0: normact across P planes -> bf16 planes.  MODE 1: f32 interleaved out.
template <int P, int BM, int BN, int K, int NN, int MODE, int WM, int WN>
__device__ __forceinline__ void gemm_core(
    unsigned short* sm, int b,
    const unsigned short* __restrict__ Ap, long planeA,
    const unsigned short* __restrict__ Wt,
    void* __restrict__ outp, long planeOut, int outOff, float sc) {
  constexpr int BK = 32;
  constexpr int RM = BM / WM, RN = BN / WN;     // per-wave tile
  constexpr int FM = RM / 32, FN = RN / 32;
  constexpr int CHA = P * BM * 4;               // A 16B-chunks per substep
  constexpr int TCH = CHA + BN * 4;
  constexpr int ITER = (TCH + 511) / 512;       // loads per thread (uniform)
  constexpr int BUFE = TCH * 8;                 // elems per sub-buffer
  constexpr int NT = K / BK;
  constexpr int NX = NN / BN;
  constexpr int NWG = (32768 / BM) * NX;

  const int tid = threadIdx.x;
  const int lane = tid & 63, wv = tid >> 6;
  const int wr = wv / WN, wc = wv % WN;
  const int ln31 = lane & 31, kh = lane >> 5;

  const int wg = (b & 7) * (NWG / 8) + (b >> 3);   // bijective XCD swizzle
  const long m0 = (long)(wg / NX) * BM;
  const int n0 = (wg % NX) * BN;

  f32x16 acc[P][FM][FN];
#pragma unroll
  for (int p = 0; p < P; ++p)
#pragma unroll
    for (int a = 0; a < FM; ++a)
#pragma unroll
      for (int c = 0; c < FN; ++c) acc[p][a][c] = (f32x16)0.f;

  auto stage = [&](unsigned short* buf, int t) {
#pragma unroll
    for (int it = 0; it < ITER; ++it) {
      int c = it * 512 + tid;
      if constexpr (ITER * 512 != TCH) {
        if (c >= TCH) c -= 512;          // duplicate a B-chunk (benign), keeps
      }                                  // per-thread vmcnt issue count uniform
      const unsigned short* src;
      if (c < CHA) {
        int p = c / (BM * 4);
        int cp = c - p * (BM * 4);
        int row = cp >> 2, sl = cp & 3;
        int slp = sl ^ ((row >> 1) & 3);
        src = Ap + (long)p * planeA + (m0 + row) * K + t * BK + slp * 8;
      } else {
        int cb = c - CHA;
        int row = cb >> 2, sl = cb & 3;
        int slp = sl ^ ((row >> 1) & 3);
        src = Wt + (long)(n0 + row) * K + t * BK + slp * 8;
      }
      gload16(src, buf + c * 8);         // single convergent issue per it
    }
  };

  auto compute = [&](const unsigned short* buf) {
#pragma unroll
    for (int ks = 0; ks < 2; ++ks) {
      bf16x8 bv[FN];
#pragma unroll
      for (int fn = 0; fn < FN; ++fn) {
        int row = wc * RN + fn * 32 + ln31;
        int s = (ks * 2 + kh) ^ ((row >> 1) & 3);
        bv[fn] = *(const bf16x8*)(buf + CHA * 8 + row * BK + s * 8);
      }
      bf16x8 av[P][FM];
#pragma unroll
      for (int p = 0; p < P; ++p)
#pragma unroll
        for (int fm = 0; fm < FM; ++fm) {
          int row = wr * RM + fm * 32 + ln31;
          int s = (ks * 2 + kh) ^ ((row >> 1) & 3);
          av[p][fm] = *(const bf16x8*)(buf + p * BM * BK + row * BK + s * 8);
        }
      __builtin_amdgcn_s_setprio(1);
#pragma unroll
      for (int p = 0; p < P; ++p)
#pragma unroll
        for (int fm = 0; fm < FM; ++fm)
#pragma unroll
          for (int fn = 0; fn < FN; ++fn)
            acc[p][fm][fn] = __builtin_amdgcn_mfma_f32_32x32x16_bf16(
                av[p][fm], bv[fn], acc[p][fm][fn], 0, 0, 0);
      __builtin_amdgcn_s_setprio(0);
    }
  };

  stage(sm, 0);
  stage(sm + BUFE, 1);
#pragma unroll
  for (int t = 0; t < NT; ++t) {
    if (t < NT - 1) vmwait<ITER>();      // step-t landed; t+1 stays in flight
    else vmwait<0>();
    __builtin_amdgcn_s_barrier();
    asm volatile("" ::: "memory");
    if (t + 2 < NT) stage(sm + ((t + 2) % 3) * BUFE, t + 2);
    compute(sm + (t % 3) * BUFE);
  }

  if constexpr (MODE == 0) {
    __hip_bfloat16* H = (__hip_bfloat16*)outp;
#pragma unroll
    for (int fm = 0; fm < FM; ++fm)
#pragma unroll
      for (int fn = 0; fn < FN; ++fn)
#pragma unroll
        for (int reg = 0; reg < 16; ++reg) {
          long row = m0 + wr * RM + fm * 32 + (reg & 3) + 8 * (reg >> 2) + 4 * kh;
          int col = n0 + wc * RN + fn * 32 + ln31;
          float vs[P];
          float n2 = 0.f;
#pragma unroll
          for (int p = 0; p < P; ++p) {
            float v = acc[p][fm][fn][reg] * sc;
            vs[p] = v;
            n2 += v * v;
          }
          float nm = (P == 1) ? fabsf(vs[0]) : sqrtf(n2);
          float sg = frcp(1.f + __expf(-nm));   // silu(n)/n == sigmoid(n)
#pragma unroll
          for (int p = 0; p < P; ++p)
            H[p * planeOut + row * NN + col] = __float2bfloat16(vs[p] * sg);
        }
  } else {
    float* O = (float*)outp;
#pragma unroll
    for (int fm = 0; fm < FM; ++fm)
#pragma unroll
      for (int fn = 0; fn < FN; ++fn)
#pragma unroll
        for (int reg = 0; reg < 16; ++reg) {
          long row = m0 + wr * RM + fm * 32 + (reg & 3) + 8 * (reg >> 2) + 4 * kh;
          int col = n0 + wc * RN + fn * 32 + ln31;
          float* base = O + row * 1920 + outOff + (long)col * P;
          if constexpr (P == 1) {
            base[0] = acc[0][fm][fn][reg] * sc;
          } else if constexpr (P == 3) {
            f32x3 v3;
#pragma unroll
            for (int p = 0; p < 3; ++p) v3[p] = acc[p][fm][fn][reg] * sc;
            *(f32x3*)base = v3;
          } else {
            f32x4v v4;
#pragma unroll
            for (int p = 0; p < 4; ++p) v4[p] = acc[p][fm][fn][reg] * sc;
            *(f32x4v*)base = v4;
            base[4] = acc[4][fm][fn][reg] * sc;
          }
        }
  }
}

// ---- fat dispatches (512 threads; longest sub-GEMM first) ------------------
__global__ __launch_bounds__(512, 2) void fat1_kernel(
    const unsigned short* __restrict__ Xp, const unsigned short* __restrict__ W,
    unsigned short* __restrict__ Hp) {
  extern __shared__ unsigned short sm[];
  int b = blockIdx.x;
  if (b < 512) {         // l0: 256x256, K=512, waves 2x4 (128x64/wave)
    gemm_core<1, 256, 256, 512, 1024, 0, 2, 4>(sm, b, Xp, 0, W, Hp, 0, 0, 0.04419417382f);
  } else if (b < 1536) { // l1: P=3, 128x128, K=256, waves 2x4 (64x32/wave)
    gemm_core<3, 128, 128, 256, 512, 0, 2, 4>(sm, b - 512, Xp + NL * 512, NL * 256, W + 524288,
                                              Hp + NL * 1024, NL * 512, 0, 0.0625f);
  } else {               // l2: P=5, 64x128, K=128, waves 2x4 (32x32/wave)
    gemm_core<5, 64, 128, 128, 256, 0, 2, 4>(sm, b - 1536, Xp + NL * 1280, NL * 128, W + 655360,
                                             Hp + NL * 2560, NL * 256, 0, 0.08838834765f);
  }
}

__global__ __launch_bounds__(512, 2) void fat2_kernel(
    const unsigned short* __restrict__ Hp, const unsigned short* __restrict__ W,
    float* __restrict__ out) {
  extern __shared__ unsigned short sm[];
  int b = blockIdx.x;
  if (b < 256) {        // l0: 256x256, K=1024
    gemm_core<1, 256, 256, 1024, 512, 1, 2, 4>(sm, b, Hp, 0, W + 688128, out, 0, 0, 0.03125f);
  } else if (b < 768) { // l1: P=3, 128x128, K=512
    gemm_core<3, 128, 128, 512, 256, 1, 2, 4>(sm, b - 256, Hp + NL * 1024, NL * 512, W + 1212416,
                                              out, 0, 512, 0.04419417382f);
  } else {              // l2: P=5, 64x128, K=256
    gemm_core<5, 64, 128, 256, 128, 1, 2, 4>(sm, b - 768, Hp + NL * 2560, NL * 256, W + 1343488,
                                             out, 0, 1280, 0.0625f);
  }
}

extern "C" void kernel_launch(void* const* d_in, const int* in_sizes, int n_in,
                              void* d_out, int out_size, void* d_ws, size_t ws_size,
                              hipStream_t stream) {
  const float* x = (const float*)d_in[0];
  const float* w1_0 = (const float*)d_in[1];
  const float* w1_1 = (const float*)d_in[2];
  const float* w1_2 = (const float*)d_in[3];
  const float* w2_0 = (const float*)d_in[4];
  const float* w2_1 = (const float*)d_in[5];
  const float* w2_2 = (const float*)d_in[6];
  float* out = (float*)d_out;

  unsigned short* Xp = (unsigned short*)d_ws;      // N*1920 bf16
  unsigned short* Hp = Xp + NL * 1920;             // N*3840 bf16
  unsigned short* W  = Hp + NL * 3840;             // 1376256 bf16 (all Wt blocks)

  {
    long total = NL * 896 + 1376256;
    prep_kernel<<<dim3((unsigned)((total + 255) / 256)), dim3(256), 0, stream>>>(
        x, w1_0, w1_1, w1_2, w2_0, w2_1, w2_2, Xp, W);
  }

  // LDS: l0 core 3 x (256+256)*32*2B = 96 KiB (max across branches)
  fat1_kernel<<<2560, 512, 98304, stream>>>(Xp, W, Hp);
  fat2_kernel<<<1280, 512, 98304, stream>>>(Hp, W, out);
}